// Round 16
// baseline (526.545 us; speedup 1.0000x reference)
//
#include <hip/hip_runtime.h>
#include <math.h>

// ---------------- constants ----------------
#define INTER 128
#define OUTD  64
#define SCAN_T 256
#define SCAN_E 1024
#define NBIN  256    // sort key bins: batch*32 + min(deg,31)
#define PNB2  512    // nodes per wpool block
#define NSLOT 64

using bf16x8 = __attribute__((ext_vector_type(8))) short;
using f32x4  = __attribute__((ext_vector_type(4))) float;

static __device__ __forceinline__ unsigned short f2bf(float f) {
    unsigned int u = __float_as_uint(f);
    u += 0x7fffu + ((u >> 16) & 1u);          // RTNE
    return (unsigned short)(u >> 16);
}
static __device__ __forceinline__ unsigned int pk2(float a, float b) {
    return (unsigned int)f2bf(a) | ((unsigned int)f2bf(b) << 16);
}
static __device__ __forceinline__ float bflo(unsigned int u) { return __uint_as_float(u << 16); }
static __device__ __forceinline__ float bfhi(unsigned int u) { return __uint_as_float(u & 0xffff0000u); }

static __device__ __forceinline__ void fma8(float* a, float w, uint4 v) {
    a[0] = fmaf(w, bflo(v.x), a[0]); a[1] = fmaf(w, bfhi(v.x), a[1]);
    a[2] = fmaf(w, bflo(v.y), a[2]); a[3] = fmaf(w, bfhi(v.y), a[3]);
    a[4] = fmaf(w, bflo(v.z), a[4]); a[5] = fmaf(w, bfhi(v.z), a[5]);
    a[6] = fmaf(w, bflo(v.w), a[6]); a[7] = fmaf(w, bfhi(v.w), a[7]);
}
static __device__ __forceinline__ void seed8(float* a, float sn, uint4 v) {
    a[0] = sn * bflo(v.x); a[1] = sn * bfhi(v.x);
    a[2] = sn * bflo(v.y); a[3] = sn * bfhi(v.y);
    a[4] = sn * bflo(v.z); a[5] = sn * bfhi(v.z);
    a[6] = sn * bflo(v.w); a[7] = sn * bfhi(v.w);
}

// ---------------- CSR build ----------------
__global__ void count_k(const int* __restrict__ dst, int* __restrict__ cnt, int E) {
    int e = blockIdx.x * 256 + threadIdx.x;
    if (e < E) atomicAdd(&cnt[dst[e]], 1);
}

__global__ void scan_block(const int* __restrict__ in, int* __restrict__ out,
                           int* __restrict__ bsums, int n) {
    __shared__ int sh[SCAN_T];
    int base = blockIdx.x * SCAN_E;
    int t = threadIdx.x;
    int v[4];
    int s = 0;
#pragma unroll
    for (int i = 0; i < 4; i++) {
        int idx = base + t * 4 + i;
        v[i] = (idx < n) ? in[idx] : 0;
        s += v[i];
    }
    sh[t] = s;
    __syncthreads();
    for (int off = 1; off < SCAN_T; off <<= 1) {
        int x = (t >= off) ? sh[t - off] : 0;
        __syncthreads();
        sh[t] += x;
        __syncthreads();
    }
    int excl = (t == 0) ? 0 : sh[t - 1];
    if (bsums && t == SCAN_T - 1) bsums[blockIdx.x] = sh[t];
#pragma unroll
    for (int i = 0; i < 4; i++) {
        int idx = base + t * 4 + i;
        if (idx < n) out[idx] = excl;
        excl += v[i];
    }
}

__global__ void scan_add(int* __restrict__ out, const int* __restrict__ bsums, int n, int total) {
    int idx = blockIdx.x * SCAN_E + threadIdx.x * 4;
    int add = bsums[blockIdx.x];
#pragma unroll
    for (int i = 0; i < 4; i++) {
        int j = idx + i;
        if (j < n) out[j] += add;
    }
    if (blockIdx.x == 0 && threadIdx.x == 0) out[n] = total;
}

// scatter edges into CSR + accumulate last-layer colsum (fused edge pass)
__global__ void scatter_cs_k(const int* __restrict__ src, const int* __restrict__ dst,
                             const int* __restrict__ rs, int* __restrict__ cursor,
                             const float* __restrict__ dinv, const int* __restrict__ batch,
                             int2* __restrict__ cw, float* __restrict__ colsum,
                             int N, int E) {
    int e = blockIdx.x * 256 + threadIdx.x;
    if (e < E) {
        int s = src[e], d = dst[e];
        float w = dinv[s] * dinv[d];
        int pos = rs[d] + atomicAdd(&cursor[d], 1);
        cw[pos] = make_int2(s, __float_as_int(w));
        atomicAdd(&colsum[(size_t)batch[d] * N + s], w);
    } else if (e < E + N) {
        int i = e - E;
        float di = dinv[i];
        atomicAdd(&colsum[(size_t)batch[i] * N + i], di * di);
    }
}

// ---------------- fused prep: dinv + key-histogram + graph bounds ----------------
__global__ __launch_bounds__(256) void prep2_k(const int* __restrict__ cnt,
                                               const int* __restrict__ batch,
                                               float* __restrict__ dinv,
                                               int* __restrict__ blockhist,
                                               int* __restrict__ gstart,
                                               int N, int G, int nblk) {
    __shared__ int hist[NBIN];
    int t = threadIdx.x;
    if (t < NBIN) hist[t] = 0;
    __syncthreads();
    int i = blockIdx.x * 256 + t;
    if (i < N) {
        int d = cnt[i];
        dinv[i] = rsqrtf((float)(d + 1));
        int b = batch[i];
        atomicAdd(&hist[b * 32 + min(d, 31)], 1);
        int prev = (i == 0) ? -1 : batch[i - 1];
        for (int g2 = prev + 1; g2 <= b; g2++) gstart[g2] = i;
        if (i == N - 1) for (int g2 = b + 1; g2 <= G; g2++) gstart[g2] = N;
    }
    __syncthreads();
    if (t < NBIN) blockhist[t * nblk + blockIdx.x] = hist[t];
}

// scatter into sorted order; srt = (node, rs0, rs1, dinv_bits)
__global__ __launch_bounds__(256) void dorder3_k(const int* __restrict__ cnt,
                                                 const int* __restrict__ batch,
                                                 const int* __restrict__ rs,
                                                 const float* __restrict__ dinv,
                                                 const int* __restrict__ offs,
                                                 int4* __restrict__ srt,
                                                 int N, int nblk) {
    __shared__ int cur[NBIN];
    int t = threadIdx.x;
    if (t < NBIN) cur[t] = 0;
    __syncthreads();
    int i = blockIdx.x * 256 + t;
    if (i >= N) return;
    int key = batch[i] * 32 + min(cnt[i], 31);
    int r = atomicAdd(&cur[key], 1);              // LDS atomic, block-local
    int p = offs[key * nblk + blockIdx.x] + r;
    srt[p] = make_int4(i, rs[i], rs[i + 1], __float_as_int(dinv[i]));
}

// ---------------- weight prep (fp32 -> bf16, transposed [n][k]) ----------------
__global__ void wprep_h(const float* __restrict__ W, unsigned short* __restrict__ Wt, int L) {
    int tid = blockIdx.x * 256 + threadIdx.x;
    if (tid >= L * INTER * INTER) return;
    int l = tid / (INTER * INTER);
    int r = tid % (INTER * INTER);
    int n = r / INTER, k = r % INTER;
    Wt[tid] = f2bf(W[(size_t)l * INTER * INTER + (size_t)k * INTER + n]);
}

// ---------------- fused input layer: h = (A_hat x) @ W_in + b_in -> bf16 ----------------
__global__ __launch_bounds__(256) void agg_in_k(const float* __restrict__ x,
                                                const int* __restrict__ rs,
                                                const int2* __restrict__ cw,
                                                const float* __restrict__ dinv,
                                                const float* __restrict__ Wi,
                                                const float* __restrict__ bi,
                                                unsigned short* __restrict__ h, int N) {
    __shared__ float2 axs[256];
    int t = threadIdx.x;
    int i = blockIdx.x * 256 + t;
    float a0 = 0.f, a1 = 0.f;
    if (i < N) {
        float di = dinv[i];
        float sn = di * di;
        float2 xv = ((const float2*)x)[i];
        a0 = sn * xv.x; a1 = sn * xv.y;
        int e0 = rs[i], e1 = rs[i + 1];
        for (int k = e0; k < e1; k += 2) {
            int2 c0 = cw[k];
            int2 c1 = (k + 1 < e1) ? cw[k + 1] : make_int2(0, 0);
            float2 x0 = ((const float2*)x)[c0.x];
            float2 x1 = ((const float2*)x)[c1.x];
            float w0 = __int_as_float(c0.y), w1 = __int_as_float(c1.y);
            a0 = fmaf(w0, x0.x, a0); a1 = fmaf(w0, x0.y, a1);
            a0 = fmaf(w1, x1.x, a0); a1 = fmaf(w1, x1.y, a1);
        }
    }
    axs[t] = make_float2(a0, a1);
    __syncthreads();
    int base = blockIdx.x * 256;
#pragma unroll
    for (int p = 0; p < 16; p++) {
        int nl = p * 16 + (t >> 4);
        int nb = base + nl;
        if (nb < N) {
            int j0 = (t & 15) * 8;
            float2 a = axs[nl];
            float4 wa0 = *(const float4*)&Wi[j0];       float4 wa1 = *(const float4*)&Wi[j0 + 4];
            float4 wb0 = *(const float4*)&Wi[128 + j0]; float4 wb1 = *(const float4*)&Wi[128 + j0 + 4];
            float4 bb0 = *(const float4*)&bi[j0];       float4 bb1 = *(const float4*)&bi[j0 + 4];
            float h0 = fmaf(a.x, wa0.x, fmaf(a.y, wb0.x, bb0.x));
            float h1 = fmaf(a.x, wa0.y, fmaf(a.y, wb0.y, bb0.y));
            float h2 = fmaf(a.x, wa0.z, fmaf(a.y, wb0.z, bb0.z));
            float h3 = fmaf(a.x, wa0.w, fmaf(a.y, wb0.w, bb0.w));
            float h4 = fmaf(a.x, wa1.x, fmaf(a.y, wb1.x, bb1.x));
            float h5 = fmaf(a.x, wa1.y, fmaf(a.y, wb1.y, bb1.y));
            float h6 = fmaf(a.x, wa1.z, fmaf(a.y, wb1.z, bb1.z));
            float h7 = fmaf(a.x, wa1.w, fmaf(a.y, wb1.w, bb1.w));
            *(uint4*)(h + (size_t)nb * 128 + j0) =
                make_uint4(pk2(h0, h1), pk2(h2, h3), pk2(h4, h5), pk2(h6, h7));
        }
    }
}

// ---------------- fused hidden layer: Hout = relu((A_hat Hin) W + b) ----------------
// 512 threads, 32 nodes/block, ONE node per 16-lane group, OCT-edge unroll
// (8 gathers in flight, ~1.02 serial rounds with degree-sorted blocks).
// Phase 2: 8 waves x 16-col slice x 2 node chunks (Wt read once per block).
// Output staged in LDS, then cooperative full-line row stores.
__global__ __launch_bounds__(512) void fused_hidden9(
    const unsigned short* __restrict__ Hin,
    const int2* __restrict__ cw,
    const int4* __restrict__ srt,
    const unsigned short* __restrict__ Wt,   // [128][128] bf16, Wt[n][k] = W[k][n]
    const float* __restrict__ bias,
    unsigned short* __restrict__ Hout, int N)
{
    __shared__ __align__(16) unsigned short T[32][136];
    __shared__ int nodeid[32];
    const int t = threadIdx.x;
    const int q = t & 15;        // 16 lanes per node
    const int gi = t >> 4;       // 0..31
    const int s = blockIdx.x * 32 + gi;
    int4 d0 = (s < N) ? srt[s] : make_int4(-1, 0, 0, 0);
    if (q == 0) nodeid[gi] = d0.x;

    float acc[8] = {0,0,0,0,0,0,0,0};
    int k0 = 0, e0 = 0;
    if (d0.x >= 0) {
        float dv = __int_as_float(d0.w);
        seed8(acc, dv * dv, *(const uint4*)(Hin + (size_t)d0.x * 128 + q * 8));
        k0 = d0.y; e0 = d0.z;
    }

    for (int k = k0; k < e0; k += 8) {
        int2 c[8];
#pragma unroll
        for (int u = 0; u < 8; u++)
            c[u] = (k + u < e0) ? cw[k + u] : make_int2(0, 0);
        uint4 v[8];
#pragma unroll
        for (int u = 0; u < 8; u++)
            v[u] = *(const uint4*)(Hin + (size_t)c[u].x * 128 + q * 8);
#pragma unroll
        for (int u = 0; u < 8; u++)
            fma8(acc, __int_as_float(c[u].y), v[u]);
    }

    *(uint4*)&T[gi][q * 8] = make_uint4(pk2(acc[0], acc[1]), pk2(acc[2], acc[3]),
                                        pk2(acc[4], acc[5]), pk2(acc[6], acc[7]));
    __syncthreads();

    // phase 2: 8 waves, 16-col slice each, 2 node chunks; W-frags loaded once
    const int wv = t >> 6;       // 0..7 -> cols [wv*16, wv*16+16)
    const int lane = t & 63;
    const int r15 = lane & 15;
    const int kg = lane >> 4;

    bf16x8 wfr[4];
    {
        const unsigned short* wrow = Wt + (size_t)(wv * 16 + r15) * 128 + kg * 8;
#pragma unroll
        for (int ks = 0; ks < 4; ks++)
            wfr[ks] = *(const bf16x8*)(wrow + ks * 32);
    }

    f32x4 a2[2];
    a2[0] = (f32x4){0.f, 0.f, 0.f, 0.f};
    a2[1] = (f32x4){0.f, 0.f, 0.f, 0.f};
#pragma unroll
    for (int nc = 0; nc < 2; nc++) {
#pragma unroll
        for (int ks = 0; ks < 4; ks++) {
            bf16x8 bfr = *(const bf16x8*)&T[nc * 16 + r15][kg * 8 + ks * 32];
            a2[nc] = __builtin_amdgcn_mfma_f32_16x16x32_bf16(wfr[ks], bfr, a2[nc], 0, 0, 0);
        }
    }
    __syncthreads();   // all waves done reading T; safe to overwrite

    // bias+relu, stage into T[node_local][col]
    {
        const int col = wv * 16 + kg * 4;
        const float4 bv = *(const float4*)(bias + col);
#pragma unroll
        for (int nc = 0; nc < 2; nc++) {
            float v0 = fmaxf(a2[nc][0] + bv.x, 0.f);
            float v1 = fmaxf(a2[nc][1] + bv.y, 0.f);
            float v2 = fmaxf(a2[nc][2] + bv.z, 0.f);
            float v3 = fmaxf(a2[nc][3] + bv.w, 0.f);
            *(uint2*)&T[nc * 16 + r15][col] = make_uint2(pk2(v0, v1), pk2(v2, v3));
        }
    }
    __syncthreads();

    // cooperative full-line stores: group gi stores its node row (16 x 16B)
    {
        int node = nodeid[gi];
        if (node >= 0)
            *(uint4*)(Hout + (size_t)node * 128 + q * 8) = *(const uint4*)&T[gi][q * 8];
    }
}

// ---------------- weighted pool over hin: gsum[slot][g][k] += sum_j colsum[g][j]*hin[j][k] ----
__global__ __launch_bounds__(256) void wpool128_k(const unsigned short* __restrict__ hin,
                                                  const float* __restrict__ colsum,
                                                  float* __restrict__ gsum, int N) {
    const int t = threadIdx.x;
    const int wv = t >> 6;          // wave handles graphs 2wv, 2wv+1
    const int lane = t & 63;
    const int f16 = lane & 15;      // 8 feats via uint4
    const int r = lane >> 4;        // 4 rows in parallel
    const int g0 = wv * 2;
    float acc[2][8];
#pragma unroll
    for (int a = 0; a < 2; a++)
#pragma unroll
        for (int b = 0; b < 8; b++) acc[a][b] = 0.f;

    int base = blockIdx.x * PNB2;
    int end = min(base + PNB2, N);
    for (int j = base + r; j < end; j += 4) {
        uint4 v = *(const uint4*)(hin + (size_t)j * 128 + f16 * 8);
        float c0 = colsum[(size_t)g0 * N + j];
        float c1 = colsum[(size_t)(g0 + 1) * N + j];
        float xv[8] = {bflo(v.x), bfhi(v.x), bflo(v.y), bfhi(v.y),
                       bflo(v.z), bfhi(v.z), bflo(v.w), bfhi(v.w)};
#pragma unroll
        for (int b = 0; b < 8; b++) {
            acc[0][b] = fmaf(c0, xv[b], acc[0][b]);
            acc[1][b] = fmaf(c1, xv[b], acc[1][b]);
        }
    }
#pragma unroll
    for (int a = 0; a < 2; a++)
#pragma unroll
        for (int b = 0; b < 8; b++) {
            float v = acc[a][b];
            v += __shfl_xor(v, 16, 64);
            v += __shfl_xor(v, 32, 64);
            acc[a][b] = v;
        }
    if (r == 0) {
        int slot = blockIdx.x & (NSLOT - 1);
        float* dstp = gsum + ((size_t)slot * 8 + g0) * 128 + f16 * 8;
#pragma unroll
        for (int a = 0; a < 2; a++)
#pragma unroll
            for (int b = 0; b < 8; b++)
                atomicAdd(&dstp[(size_t)a * 128 + b], acc[a][b]);
    }
}

// ---------------- final: sg = sum slots; out = sigmoid(sg @ W_out / c + b) ----------------
__global__ void final6_k(const float* __restrict__ gsum, const int* __restrict__ gstart,
                         const float* __restrict__ W_out, const float* __restrict__ b_out,
                         float* __restrict__ out) {
    __shared__ float sg[8][128];
    int t = threadIdx.x;  // 512
    for (int i = t; i < 1024; i += 512) {
        int g = i >> 7, k = i & 127;
        float s = 0.f;
        for (int sl = 0; sl < NSLOT; sl++) s += gsum[((size_t)sl * 8 + g) * 128 + k];
        sg[g][k] = s;
    }
    __syncthreads();
    int g = t / 64, f = t % 64;
    float dot = 0.f;
    for (int k = 0; k < 128; k++) dot = fmaf(sg[g][k], W_out[k * 64 + f], dot);
    int c = gstart[g + 1] - gstart[g];
    float v = dot / (float)max(c, 1) + b_out[f];
    out[g * 64 + f] = 1.f / (1.f + expf(-v));
}

// ---------------- launch ----------------
extern "C" void kernel_launch(void* const* d_in, const int* in_sizes, int n_in,
                              void* d_out, int out_size, void* d_ws, size_t ws_size,
                              hipStream_t stream) {
    const float* x     = (const float*)d_in[0];
    const int*   ei    = (const int*)d_in[1];
    const int*   batch = (const int*)d_in[2];
    const float* W_in  = (const float*)d_in[3];
    const float* b_in  = (const float*)d_in[4];
    const float* W_h   = (const float*)d_in[5];
    const float* b_h   = (const float*)d_in[6];
    const float* W_out = (const float*)d_in[7];
    const float* b_out = (const float*)d_in[8];

    const int N = in_sizes[2];
    const int E = in_sizes[1] / 2;
    const int L = in_sizes[5] / (INTER * INTER);
    const int G = 8;
    const int* src = ei;
    const int* dst = ei + E;
    const int nblk = (N + 255) / 256;
    const int nbh = NBIN * nblk;              // blockhist size

    char* ws = (char*)d_ws;
    size_t off = 0;
    auto alloc = [&](size_t bytes) -> void* {
        void* p = ws + off;
        off += (bytes + 255) & ~(size_t)255;
        return p;
    };
    int*   cnt    = (int*)alloc((size_t)N * 4);
    int*   cursor = (int*)alloc((size_t)N * 4);   // adjacent to cnt: one memset covers both
    int*   rs     = (int*)alloc((size_t)(N + 1) * 4);
    int*   bsums  = (int*)alloc(4096);
    float* dinv   = (float*)alloc((size_t)N * 4);
    int2*  cw     = (int2*)alloc((size_t)E * 8);
    unsigned short* h   = (unsigned short*)alloc((size_t)N * INTER * 2);
    unsigned short* h2  = (unsigned short*)alloc((size_t)N * INTER * 2);
    unsigned short* Wht = (unsigned short*)alloc((size_t)L * INTER * INTER * 2);
    float* colsum = (float*)alloc((size_t)8 * N * 4);
    float* gsum   = (float*)alloc((size_t)NSLOT * 8 * 128 * 4);
    int*   gstart = (int*)alloc((G + 1) * 4);
    int*   bh     = (int*)alloc((size_t)(nbh + 1) * 4);
    int4*  srt    = (int4*)alloc((size_t)N * 16);
    (void)ws_size; (void)n_in;

    hipMemsetAsync(cnt, 0, (size_t)N * 8, stream);   // cnt + cursor (adjacent)
    hipMemsetAsync(colsum, 0, (size_t)8 * N * 4, stream);
    hipMemsetAsync(gsum, 0, (size_t)NSLOT * 8 * 128 * 4, stream);

    // CSR build
    count_k<<<(E + 255) / 256, 256, 0, stream>>>(dst, cnt, E);
    int nsb = (N + SCAN_E - 1) / SCAN_E;
    scan_block<<<nsb, SCAN_T, 0, stream>>>(cnt, rs, bsums, N);
    scan_block<<<1, SCAN_T, 0, stream>>>(bsums, bsums, nullptr, nsb);
    scan_add<<<nsb, SCAN_T, 0, stream>>>(rs, bsums, N, E);
    prep2_k<<<nblk, 256, 0, stream>>>(cnt, batch, dinv, bh, gstart, N, G, nblk);
    scatter_cs_k<<<(E + N + 255) / 256, 256, 0, stream>>>(src, dst, rs, cursor, dinv, batch,
                                                          cw, colsum, N, E);

    // counting-sort scan + scatter -> srt
    int nsb2 = (nbh + SCAN_E - 1) / SCAN_E;
    scan_block<<<nsb2, SCAN_T, 0, stream>>>(bh, bh, bsums, nbh);
    scan_block<<<1, SCAN_T, 0, stream>>>(bsums, bsums, nullptr, nsb2);
    scan_add<<<nsb2, SCAN_T, 0, stream>>>(bh, bsums, nbh, N);
    dorder3_k<<<nblk, 256, 0, stream>>>(cnt, batch, rs, dinv, bh, srt, N, nblk);

    // weight prep
    wprep_h<<<(L * INTER * INTER + 255) / 256, 256, 0, stream>>>(W_h, Wht, L);

    // input layer (fused aggregate + transform)
    agg_in_k<<<nblk, 256, 0, stream>>>(x, rs, cw, dinv, W_in, b_in, h, N);

    // hidden layers (fused gather + MFMA transform), ping-pong h <-> h2
    unsigned short* hin = h;
    unsigned short* hout = h2;
    for (int l = 0; l < L; l++) {
        fused_hidden9<<<(N + 31) / 32, 512, 0, stream>>>(
            hin, cw, srt, Wht + (size_t)l * INTER * INTER, b_h + (size_t)l * INTER, hout, N);
        unsigned short* tmp = hin; hin = hout; hout = tmp;
    }

    // output layer: gather-free pooling over hin, then tiny fp32 matmul + sigmoid
    wpool128_k<<<(N + PNB2 - 1) / PNB2, 256, 0, stream>>>(hin, colsum, gsum, N);
    final6_k<<<1, 512, 0, stream>>>(gsum, gstart, W_out, b_out, (float*)d_out);
}

// Round 17
// 485.456 us; speedup vs baseline: 1.0846x; 1.0846x over previous
//
#include <hip/hip_runtime.h>
#include <math.h>

// ---------------- constants ----------------
#define INTER 128
#define OUTD  64
#define SCAN_T 256
#define SCAN_E 1024
#define NBIN  256    // sort key bins: batch*32 + min(deg,31)
#define NSLOT 64

using bf16x8 = __attribute__((ext_vector_type(8))) short;
using f32x4  = __attribute__((ext_vector_type(4))) float;

static __device__ __forceinline__ unsigned short f2bf(float f) {
    unsigned int u = __float_as_uint(f);
    u += 0x7fffu + ((u >> 16) & 1u);          // RTNE
    return (unsigned short)(u >> 16);
}
static __device__ __forceinline__ unsigned int pk2(float a, float b) {
    return (unsigned int)f2bf(a) | ((unsigned int)f2bf(b) << 16);
}
static __device__ __forceinline__ float bflo(unsigned int u) { return __uint_as_float(u << 16); }
static __device__ __forceinline__ float bfhi(unsigned int u) { return __uint_as_float(u & 0xffff0000u); }

static __device__ __forceinline__ void fma8(float* a, float w, uint4 v) {
    a[0] = fmaf(w, bflo(v.x), a[0]); a[1] = fmaf(w, bfhi(v.x), a[1]);
    a[2] = fmaf(w, bflo(v.y), a[2]); a[3] = fmaf(w, bfhi(v.y), a[3]);
    a[4] = fmaf(w, bflo(v.z), a[4]); a[5] = fmaf(w, bfhi(v.z), a[5]);
    a[6] = fmaf(w, bflo(v.w), a[6]); a[7] = fmaf(w, bfhi(v.w), a[7]);
}
static __device__ __forceinline__ void seed8(float* a, float sn, uint4 v) {
    a[0] = sn * bflo(v.x); a[1] = sn * bfhi(v.x);
    a[2] = sn * bflo(v.y); a[3] = sn * bfhi(v.y);
    a[4] = sn * bflo(v.z); a[5] = sn * bfhi(v.z);
    a[6] = sn * bflo(v.w); a[7] = sn * bfhi(v.w);
}

// ---------------- CSR build ----------------
__global__ void count_k(const int* __restrict__ dst, int* __restrict__ cnt, int E) {
    int e = blockIdx.x * 256 + threadIdx.x;
    if (e < E) atomicAdd(&cnt[dst[e]], 1);
}

__global__ void scan_block(const int* __restrict__ in, int* __restrict__ out,
                           int* __restrict__ bsums, int n) {
    __shared__ int sh[SCAN_T];
    int base = blockIdx.x * SCAN_E;
    int t = threadIdx.x;
    int v[4];
    int s = 0;
#pragma unroll
    for (int i = 0; i < 4; i++) {
        int idx = base + t * 4 + i;
        v[i] = (idx < n) ? in[idx] : 0;
        s += v[i];
    }
    sh[t] = s;
    __syncthreads();
    for (int off = 1; off < SCAN_T; off <<= 1) {
        int x = (t >= off) ? sh[t - off] : 0;
        __syncthreads();
        sh[t] += x;
        __syncthreads();
    }
    int excl = (t == 0) ? 0 : sh[t - 1];
    if (bsums && t == SCAN_T - 1) bsums[blockIdx.x] = sh[t];
#pragma unroll
    for (int i = 0; i < 4; i++) {
        int idx = base + t * 4 + i;
        if (idx < n) out[idx] = excl;
        excl += v[i];
    }
}

__global__ void scan_add(int* __restrict__ out, const int* __restrict__ bsums, int n, int total) {
    int idx = blockIdx.x * SCAN_E + threadIdx.x * 4;
    int add = bsums[blockIdx.x];
#pragma unroll
    for (int i = 0; i < 4; i++) {
        int j = idx + i;
        if (j < n) out[j] += add;
    }
    if (blockIdx.x == 0 && threadIdx.x == 0) out[n] = total;
}

__global__ void scatter_k(const int* __restrict__ src, const int* __restrict__ dst,
                          const int* __restrict__ rs, int* __restrict__ cursor,
                          const float* __restrict__ dinv,
                          int2* __restrict__ cw, int E) {
    int e = blockIdx.x * 256 + threadIdx.x;
    if (e >= E) return;
    int s = src[e], d = dst[e];
    int pos = rs[d] + atomicAdd(&cursor[d], 1);
    cw[pos] = make_int2(s, __float_as_int(dinv[s] * dinv[d]));
}

// ---------------- fused prep: dinv + key-histogram + graph bounds ----------------
__global__ __launch_bounds__(256) void prep2_k(const int* __restrict__ cnt,
                                               const int* __restrict__ batch,
                                               float* __restrict__ dinv,
                                               int* __restrict__ blockhist,
                                               int* __restrict__ gstart,
                                               int N, int G, int nblk) {
    __shared__ int hist[NBIN];
    int t = threadIdx.x;
    if (t < NBIN) hist[t] = 0;
    __syncthreads();
    int i = blockIdx.x * 256 + t;
    if (i < N) {
        int d = cnt[i];
        dinv[i] = rsqrtf((float)(d + 1));
        int b = batch[i];
        atomicAdd(&hist[b * 32 + min(d, 31)], 1);
        int prev = (i == 0) ? -1 : batch[i - 1];
        for (int g2 = prev + 1; g2 <= b; g2++) gstart[g2] = i;
        if (i == N - 1) for (int g2 = b + 1; g2 <= G; g2++) gstart[g2] = N;
    }
    __syncthreads();
    if (t < NBIN) blockhist[t * nblk + blockIdx.x] = hist[t];
}

// scatter into sorted order; srt = (node, rs0, rs1, dinv_bits)
__global__ __launch_bounds__(256) void dorder3_k(const int* __restrict__ cnt,
                                                 const int* __restrict__ batch,
                                                 const int* __restrict__ rs,
                                                 const float* __restrict__ dinv,
                                                 const int* __restrict__ offs,
                                                 int4* __restrict__ srt,
                                                 int N, int nblk) {
    __shared__ int cur[NBIN];
    int t = threadIdx.x;
    if (t < NBIN) cur[t] = 0;
    __syncthreads();
    int i = blockIdx.x * 256 + t;
    if (i >= N) return;
    int key = batch[i] * 32 + min(cnt[i], 31);
    int r = atomicAdd(&cur[key], 1);              // LDS atomic, block-local
    int p = offs[key * nblk + blockIdx.x] + r;
    srt[p] = make_int4(i, rs[i], rs[i + 1], __float_as_int(dinv[i]));
}

// ---------------- weight prep (fp32 -> bf16, transposed [n][k]) ----------------
__global__ void wprep_h(const float* __restrict__ W, unsigned short* __restrict__ Wt, int L) {
    int tid = blockIdx.x * 256 + threadIdx.x;
    if (tid >= L * INTER * INTER) return;
    int l = tid / (INTER * INTER);
    int r = tid % (INTER * INTER);
    int n = r / INTER, k = r % INTER;
    Wt[tid] = f2bf(W[(size_t)l * INTER * INTER + (size_t)k * INTER + n]);
}

// ---------------- fused input layer: h = (A_hat x) @ W_in + b_in -> bf16 ----------------
__global__ __launch_bounds__(256) void agg_in_k(const float* __restrict__ x,
                                                const int* __restrict__ rs,
                                                const int2* __restrict__ cw,
                                                const float* __restrict__ dinv,
                                                const float* __restrict__ Wi,
                                                const float* __restrict__ bi,
                                                unsigned short* __restrict__ h, int N) {
    __shared__ float2 axs[256];
    int t = threadIdx.x;
    int i = blockIdx.x * 256 + t;
    float a0 = 0.f, a1 = 0.f;
    if (i < N) {
        float di = dinv[i];
        float sn = di * di;
        float2 xv = ((const float2*)x)[i];
        a0 = sn * xv.x; a1 = sn * xv.y;
        int e0 = rs[i], e1 = rs[i + 1];
        for (int k = e0; k < e1; k += 2) {
            int2 c0 = cw[k];
            int2 c1 = (k + 1 < e1) ? cw[k + 1] : make_int2(0, 0);
            float2 x0 = ((const float2*)x)[c0.x];
            float2 x1 = ((const float2*)x)[c1.x];
            float w0 = __int_as_float(c0.y), w1 = __int_as_float(c1.y);
            a0 = fmaf(w0, x0.x, a0); a1 = fmaf(w0, x0.y, a1);
            a0 = fmaf(w1, x1.x, a0); a1 = fmaf(w1, x1.y, a1);
        }
    }
    axs[t] = make_float2(a0, a1);
    __syncthreads();
    int base = blockIdx.x * 256;
#pragma unroll
    for (int p = 0; p < 16; p++) {
        int nl = p * 16 + (t >> 4);
        int nb = base + nl;
        if (nb < N) {
            int j0 = (t & 15) * 8;
            float2 a = axs[nl];
            float4 wa0 = *(const float4*)&Wi[j0];       float4 wa1 = *(const float4*)&Wi[j0 + 4];
            float4 wb0 = *(const float4*)&Wi[128 + j0]; float4 wb1 = *(const float4*)&Wi[128 + j0 + 4];
            float4 bb0 = *(const float4*)&bi[j0];       float4 bb1 = *(const float4*)&bi[j0 + 4];
            float h0 = fmaf(a.x, wa0.x, fmaf(a.y, wb0.x, bb0.x));
            float h1 = fmaf(a.x, wa0.y, fmaf(a.y, wb0.y, bb0.y));
            float h2 = fmaf(a.x, wa0.z, fmaf(a.y, wb0.z, bb0.z));
            float h3 = fmaf(a.x, wa0.w, fmaf(a.y, wb0.w, bb0.w));
            float h4 = fmaf(a.x, wa1.x, fmaf(a.y, wb1.x, bb1.x));
            float h5 = fmaf(a.x, wa1.y, fmaf(a.y, wb1.y, bb1.y));
            float h6 = fmaf(a.x, wa1.z, fmaf(a.y, wb1.z, bb1.z));
            float h7 = fmaf(a.x, wa1.w, fmaf(a.y, wb1.w, bb1.w));
            *(uint4*)(h + (size_t)nb * 128 + j0) =
                make_uint4(pk2(h0, h1), pk2(h2, h3), pk2(h4, h5), pk2(h6, h7));
        }
    }
}

// ---------------- fused hidden layer (layers 0..L-2): Hout = relu((A_hat Hin) W + b) ----------------
// dual-node quad-edge gather (8 in flight), LDS-staged output, coop full-line stores.
__global__ __launch_bounds__(256) void fused_hidden8(
    const unsigned short* __restrict__ Hin,
    const int2* __restrict__ cw,
    const int4* __restrict__ srt,
    const unsigned short* __restrict__ Wt,   // [128][128] bf16, Wt[n][k] = W[k][n]
    const float* __restrict__ bias,
    unsigned short* __restrict__ Hout, int N)
{
    __shared__ __align__(16) unsigned short T[32][136];
    __shared__ int nodeid[32];
    const int t = threadIdx.x;
    const int q = t & 15;        // 16 lanes per node
    const int gi = t >> 4;       // 0..15
    const int sA = blockIdx.x * 32 + gi;
    const int sB = sA + 16;
    int4 dA = (sA < N) ? srt[sA] : make_int4(-1, 0, 0, 0);
    int4 dB = (sB < N) ? srt[sB] : make_int4(-1, 0, 0, 0);
    if (q == 0) {
        nodeid[gi]      = dA.x;
        nodeid[gi + 16] = dB.x;
    }

    float accA[8] = {0,0,0,0,0,0,0,0}, accB[8] = {0,0,0,0,0,0,0,0};
    int kA = 0, eA = 0, kB = 0, eB = 0;
    if (dA.x >= 0) {
        float dv = __int_as_float(dA.w);
        seed8(accA, dv * dv, *(const uint4*)(Hin + (size_t)dA.x * 128 + q * 8));
        kA = dA.y; eA = dA.z;
    }
    if (dB.x >= 0) {
        float dv = __int_as_float(dB.w);
        seed8(accB, dv * dv, *(const uint4*)(Hin + (size_t)dB.x * 128 + q * 8));
        kB = dB.y; eB = dB.z;
    }

    while (kA < eA || kB < eB) {
        int2 cA0 = (kA     < eA) ? cw[kA]     : make_int2(0, 0);
        int2 cA1 = (kA + 1 < eA) ? cw[kA + 1] : make_int2(0, 0);
        int2 cA2 = (kA + 2 < eA) ? cw[kA + 2] : make_int2(0, 0);
        int2 cA3 = (kA + 3 < eA) ? cw[kA + 3] : make_int2(0, 0);
        int2 cB0 = (kB     < eB) ? cw[kB]     : make_int2(0, 0);
        int2 cB1 = (kB + 1 < eB) ? cw[kB + 1] : make_int2(0, 0);
        int2 cB2 = (kB + 2 < eB) ? cw[kB + 2] : make_int2(0, 0);
        int2 cB3 = (kB + 3 < eB) ? cw[kB + 3] : make_int2(0, 0);
        uint4 vA0 = *(const uint4*)(Hin + (size_t)cA0.x * 128 + q * 8);
        uint4 vA1 = *(const uint4*)(Hin + (size_t)cA1.x * 128 + q * 8);
        uint4 vA2 = *(const uint4*)(Hin + (size_t)cA2.x * 128 + q * 8);
        uint4 vA3 = *(const uint4*)(Hin + (size_t)cA3.x * 128 + q * 8);
        uint4 vB0 = *(const uint4*)(Hin + (size_t)cB0.x * 128 + q * 8);
        uint4 vB1 = *(const uint4*)(Hin + (size_t)cB1.x * 128 + q * 8);
        uint4 vB2 = *(const uint4*)(Hin + (size_t)cB2.x * 128 + q * 8);
        uint4 vB3 = *(const uint4*)(Hin + (size_t)cB3.x * 128 + q * 8);
        fma8(accA, __int_as_float(cA0.y), vA0);
        fma8(accA, __int_as_float(cA1.y), vA1);
        fma8(accA, __int_as_float(cA2.y), vA2);
        fma8(accA, __int_as_float(cA3.y), vA3);
        fma8(accB, __int_as_float(cB0.y), vB0);
        fma8(accB, __int_as_float(cB1.y), vB1);
        fma8(accB, __int_as_float(cB2.y), vB2);
        fma8(accB, __int_as_float(cB3.y), vB3);
        kA += 4; kB += 4;
    }

    {
        uint4 oA = make_uint4(pk2(accA[0], accA[1]), pk2(accA[2], accA[3]),
                              pk2(accA[4], accA[5]), pk2(accA[6], accA[7]));
        uint4 oB = make_uint4(pk2(accB[0], accB[1]), pk2(accB[2], accB[3]),
                              pk2(accB[4], accB[5]), pk2(accB[6], accB[7]));
        *(uint4*)&T[gi][q * 8] = oA;
        *(uint4*)&T[gi + 16][q * 8] = oB;
    }
    __syncthreads();

    // phase 2: MFMA from T
    const int wv = t >> 6;       // wave -> col slice [wv*32, wv*32+32)
    const int lane = t & 63;
    const int r15 = lane & 15;
    const int kg = lane >> 4;

    bf16x8 bfr[2][4];
#pragma unroll
    for (int nc = 0; nc < 2; nc++)
#pragma unroll
        for (int ks = 0; ks < 4; ks++)
            bfr[nc][ks] = *(const bf16x8*)&T[nc * 16 + r15][kg * 8 + ks * 32];

    f32x4 acc[2][2];
#pragma unroll
    for (int nc = 0; nc < 2; nc++)
#pragma unroll
        for (int c = 0; c < 2; c++) acc[nc][c] = (f32x4){0.f, 0.f, 0.f, 0.f};

#pragma unroll
    for (int c = 0; c < 2; c++) {
        const unsigned short* wrow = Wt + (size_t)(wv * 32 + c * 16 + r15) * 128 + kg * 8;
#pragma unroll
        for (int ks = 0; ks < 4; ks++) {
            bf16x8 afr = *(const bf16x8*)(wrow + ks * 32);
            acc[0][c] = __builtin_amdgcn_mfma_f32_16x16x32_bf16(afr, bfr[0][ks], acc[0][c], 0, 0, 0);
            acc[1][c] = __builtin_amdgcn_mfma_f32_16x16x32_bf16(afr, bfr[1][ks], acc[1][c], 0, 0, 0);
        }
    }
    __syncthreads();   // all waves done reading T; safe to overwrite

    // bias+relu, stage results into T[node_local][col]
#pragma unroll
    for (int nc = 0; nc < 2; nc++) {
#pragma unroll
        for (int c = 0; c < 2; c++) {
            int col = wv * 32 + c * 16 + kg * 4;
            float4 bv = *(const float4*)(bias + col);
            float v0 = fmaxf(acc[nc][c][0] + bv.x, 0.f);
            float v1 = fmaxf(acc[nc][c][1] + bv.y, 0.f);
            float v2 = fmaxf(acc[nc][c][2] + bv.z, 0.f);
            float v3 = fmaxf(acc[nc][c][3] + bv.w, 0.f);
            *(uint2*)&T[nc * 16 + r15][col] = make_uint2(pk2(v0, v1), pk2(v2, v3));
        }
    }
    __syncthreads();

    // cooperative full-line stores: 16 lanes x 16B = one 256B row per group
#pragma unroll
    for (int p = 0; p < 2; p++) {
        int row = p * 16 + gi;
        int node = nodeid[row];
        if (node >= 0) {
            *(uint4*)(Hout + (size_t)node * 128 + q * 8) = *(const uint4*)&T[row][q * 8];
        }
    }
}

// ---------------- last hidden layer + pooling: gsum += colsum-weighted relu(conv) ----------------
// Identical to fused_hidden8 through output staging; epilogue pools instead of storing.
__global__ __launch_bounds__(256) void fused_hidden_last(
    const unsigned short* __restrict__ Hin,
    const int2* __restrict__ cw,
    const int4* __restrict__ srt,
    const unsigned short* __restrict__ Wt,
    const float* __restrict__ bias,
    const float* __restrict__ colsum,   // [8][N]
    float* __restrict__ gsum,           // [NSLOT][8][128]
    int N)
{
    __shared__ __align__(16) unsigned short T[32][136];
    __shared__ int nodeid[32];
    __shared__ float P[2][8][128];
    const int t = threadIdx.x;
    const int q = t & 15;
    const int gi = t >> 4;
    const int sA = blockIdx.x * 32 + gi;
    const int sB = sA + 16;
    int4 dA = (sA < N) ? srt[sA] : make_int4(-1, 0, 0, 0);
    int4 dB = (sB < N) ? srt[sB] : make_int4(-1, 0, 0, 0);
    if (q == 0) {
        nodeid[gi]      = dA.x;
        nodeid[gi + 16] = dB.x;
    }

    float accA[8] = {0,0,0,0,0,0,0,0}, accB[8] = {0,0,0,0,0,0,0,0};
    int kA = 0, eA = 0, kB = 0, eB = 0;
    if (dA.x >= 0) {
        float dv = __int_as_float(dA.w);
        seed8(accA, dv * dv, *(const uint4*)(Hin + (size_t)dA.x * 128 + q * 8));
        kA = dA.y; eA = dA.z;
    }
    if (dB.x >= 0) {
        float dv = __int_as_float(dB.w);
        seed8(accB, dv * dv, *(const uint4*)(Hin + (size_t)dB.x * 128 + q * 8));
        kB = dB.y; eB = dB.z;
    }

    while (kA < eA || kB < eB) {
        int2 cA0 = (kA     < eA) ? cw[kA]     : make_int2(0, 0);
        int2 cA1 = (kA + 1 < eA) ? cw[kA + 1] : make_int2(0, 0);
        int2 cA2 = (kA + 2 < eA) ? cw[kA + 2] : make_int2(0, 0);
        int2 cA3 = (kA + 3 < eA) ? cw[kA + 3] : make_int2(0, 0);
        int2 cB0 = (kB     < eB) ? cw[kB]     : make_int2(0, 0);
        int2 cB1 = (kB + 1 < eB) ? cw[kB + 1] : make_int2(0, 0);
        int2 cB2 = (kB + 2 < eB) ? cw[kB + 2] : make_int2(0, 0);
        int2 cB3 = (kB + 3 < eB) ? cw[kB + 3] : make_int2(0, 0);
        uint4 vA0 = *(const uint4*)(Hin + (size_t)cA0.x * 128 + q * 8);
        uint4 vA1 = *(const uint4*)(Hin + (size_t)cA1.x * 128 + q * 8);
        uint4 vA2 = *(const uint4*)(Hin + (size_t)cA2.x * 128 + q * 8);
        uint4 vA3 = *(const uint4*)(Hin + (size_t)cA3.x * 128 + q * 8);
        uint4 vB0 = *(const uint4*)(Hin + (size_t)cB0.x * 128 + q * 8);
        uint4 vB1 = *(const uint4*)(Hin + (size_t)cB1.x * 128 + q * 8);
        uint4 vB2 = *(const uint4*)(Hin + (size_t)cB2.x * 128 + q * 8);
        uint4 vB3 = *(const uint4*)(Hin + (size_t)cB3.x * 128 + q * 8);
        fma8(accA, __int_as_float(cA0.y), vA0);
        fma8(accA, __int_as_float(cA1.y), vA1);
        fma8(accA, __int_as_float(cA2.y), vA2);
        fma8(accA, __int_as_float(cA3.y), vA3);
        fma8(accB, __int_as_float(cB0.y), vB0);
        fma8(accB, __int_as_float(cB1.y), vB1);
        fma8(accB, __int_as_float(cB2.y), vB2);
        fma8(accB, __int_as_float(cB3.y), vB3);
        kA += 4; kB += 4;
    }

    {
        uint4 oA = make_uint4(pk2(accA[0], accA[1]), pk2(accA[2], accA[3]),
                              pk2(accA[4], accA[5]), pk2(accA[6], accA[7]));
        uint4 oB = make_uint4(pk2(accB[0], accB[1]), pk2(accB[2], accB[3]),
                              pk2(accB[4], accB[5]), pk2(accB[6], accB[7]));
        *(uint4*)&T[gi][q * 8] = oA;
        *(uint4*)&T[gi + 16][q * 8] = oB;
    }
    __syncthreads();

    const int wv = t >> 6;
    const int lane = t & 63;
    const int r15 = lane & 15;
    const int kg = lane >> 4;

    bf16x8 bfr[2][4];
#pragma unroll
    for (int nc = 0; nc < 2; nc++)
#pragma unroll
        for (int ks = 0; ks < 4; ks++)
            bfr[nc][ks] = *(const bf16x8*)&T[nc * 16 + r15][kg * 8 + ks * 32];

    f32x4 acc[2][2];
#pragma unroll
    for (int nc = 0; nc < 2; nc++)
#pragma unroll
        for (int c = 0; c < 2; c++) acc[nc][c] = (f32x4){0.f, 0.f, 0.f, 0.f};

#pragma unroll
    for (int c = 0; c < 2; c++) {
        const unsigned short* wrow = Wt + (size_t)(wv * 32 + c * 16 + r15) * 128 + kg * 8;
#pragma unroll
        for (int ks = 0; ks < 4; ks++) {
            bf16x8 afr = *(const bf16x8*)(wrow + ks * 32);
            acc[0][c] = __builtin_amdgcn_mfma_f32_16x16x32_bf16(afr, bfr[0][ks], acc[0][c], 0, 0, 0);
            acc[1][c] = __builtin_amdgcn_mfma_f32_16x16x32_bf16(afr, bfr[1][ks], acc[1][c], 0, 0, 0);
        }
    }
    __syncthreads();

    // bias+relu, stage h4 rows into T
#pragma unroll
    for (int nc = 0; nc < 2; nc++) {
#pragma unroll
        for (int c = 0; c < 2; c++) {
            int col = wv * 32 + c * 16 + kg * 4;
            float4 bv = *(const float4*)(bias + col);
            float v0 = fmaxf(acc[nc][c][0] + bv.x, 0.f);
            float v1 = fmaxf(acc[nc][c][1] + bv.y, 0.f);
            float v2 = fmaxf(acc[nc][c][2] + bv.z, 0.f);
            float v3 = fmaxf(acc[nc][c][3] + bv.w, 0.f);
            *(uint2*)&T[nc * 16 + r15][col] = make_uint2(pk2(v0, v1), pk2(v2, v3));
        }
    }
    __syncthreads();

    // pooling epilogue: thread (f, half) accumulates 16 rows x 8 graphs
    {
        const int f = t & 127;
        const int half = t >> 7;
        float pacc[8] = {0,0,0,0,0,0,0,0};
        for (int r = 0; r < 16; r++) {
            int row = half * 16 + r;
            int node = nodeid[row];
            if (node < 0) continue;
            float val = bflo((unsigned int)T[row][f]);
#pragma unroll
            for (int g = 0; g < 8; g++)
                pacc[g] = fmaf(colsum[(size_t)g * N + node], val, pacc[g]);
        }
#pragma unroll
        for (int g = 0; g < 8; g++) P[half][g][f] = pacc[g];
        __syncthreads();
        if (half == 0) {
            int slot = blockIdx.x & (NSLOT - 1);
#pragma unroll
            for (int g = 0; g < 8; g++)
                atomicAdd(&gsum[((size_t)slot * 8 + g) * 128 + f], P[0][g][f] + P[1][g][f]);
        }
    }
}

// ---------------- last-layer colsum: colsum[g][j] = sum_{i in g} A_hat_ij ----------------
__global__ void colsum_k(const int* __restrict__ src, const int* __restrict__ dst,
                         const int* __restrict__ batch, const float* __restrict__ dinv,
                         float* __restrict__ colsum, int N, int E) {
    int e = blockIdx.x * 256 + threadIdx.x;
    if (e < E) {
        int s = src[e], d = dst[e];
        atomicAdd(&colsum[(size_t)batch[d] * N + s], dinv[s] * dinv[d]);
    } else if (e < E + N) {
        int i = e - E;
        float di = dinv[i];
        atomicAdd(&colsum[(size_t)batch[i] * N + i], di * di);
    }
}

// ---------------- final: sg = sum slots; out = sigmoid(sg @ W_out / c + b) ----------------
__global__ void final6_k(const float* __restrict__ gsum, const int* __restrict__ gstart,
                         const float* __restrict__ W_out, const float* __restrict__ b_out,
                         float* __restrict__ out) {
    __shared__ float sg[8][128];
    int t = threadIdx.x;  // 512
    for (int i = t; i < 1024; i += 512) {
        int g = i >> 7, k = i & 127;
        float s = 0.f;
        for (int sl = 0; sl < NSLOT; sl++) s += gsum[((size_t)sl * 8 + g) * 128 + k];
        sg[g][k] = s;
    }
    __syncthreads();
    int g = t / 64, f = t % 64;
    float dot = 0.f;
    for (int k = 0; k < 128; k++) dot = fmaf(sg[g][k], W_out[k * 64 + f], dot);
    int c = gstart[g + 1] - gstart[g];
    float v = dot / (float)max(c, 1) + b_out[f];
    out[g * 64 + f] = 1.f / (1.f + expf(-v));
}

// ---------------- launch ----------------
extern "C" void kernel_launch(void* const* d_in, const int* in_sizes, int n_in,
                              void* d_out, int out_size, void* d_ws, size_t ws_size,
                              hipStream_t stream) {
    const float* x     = (const float*)d_in[0];
    const int*   ei    = (const int*)d_in[1];
    const int*   batch = (const int*)d_in[2];
    const float* W_in  = (const float*)d_in[3];
    const float* b_in  = (const float*)d_in[4];
    const float* W_h   = (const float*)d_in[5];
    const float* b_h   = (const float*)d_in[6];
    const float* W_out = (const float*)d_in[7];
    const float* b_out = (const float*)d_in[8];

    const int N = in_sizes[2];
    const int E = in_sizes[1] / 2;
    const int L = in_sizes[5] / (INTER * INTER);
    const int G = 8;
    const int* src = ei;
    const int* dst = ei + E;
    const int nblk = (N + 255) / 256;
    const int nbh = NBIN * nblk;              // blockhist size

    char* ws = (char*)d_ws;
    size_t off = 0;
    auto alloc = [&](size_t bytes) -> void* {
        void* p = ws + off;
        off += (bytes + 255) & ~(size_t)255;
        return p;
    };
    int*   cnt    = (int*)alloc((size_t)N * 4);
    int*   cursor = (int*)alloc((size_t)N * 4);   // adjacent to cnt: one memset covers both
    int*   rs     = (int*)alloc((size_t)(N + 1) * 4);
    int*   bsums  = (int*)alloc(4096);
    float* dinv   = (float*)alloc((size_t)N * 4);
    int2*  cw     = (int2*)alloc((size_t)E * 8);
    unsigned short* h   = (unsigned short*)alloc((size_t)N * INTER * 2);
    unsigned short* h2  = (unsigned short*)alloc((size_t)N * INTER * 2);
    unsigned short* Wht = (unsigned short*)alloc((size_t)L * INTER * INTER * 2);
    float* colsum = (float*)alloc((size_t)8 * N * 4);
    float* gsum   = (float*)alloc((size_t)NSLOT * 8 * 128 * 4);
    int*   gstart = (int*)alloc((G + 1) * 4);
    int*   bh     = (int*)alloc((size_t)(nbh + 1) * 4);
    int4*  srt    = (int4*)alloc((size_t)N * 16);
    (void)ws_size; (void)n_in;

    hipMemsetAsync(cnt, 0, (size_t)N * 8, stream);   // cnt + cursor (adjacent)
    hipMemsetAsync(colsum, 0, (size_t)8 * N * 4, stream);
    hipMemsetAsync(gsum, 0, (size_t)NSLOT * 8 * 128 * 4, stream);

    // CSR build
    count_k<<<(E + 255) / 256, 256, 0, stream>>>(dst, cnt, E);
    int nsb = (N + SCAN_E - 1) / SCAN_E;
    scan_block<<<nsb, SCAN_T, 0, stream>>>(cnt, rs, bsums, N);
    scan_block<<<1, SCAN_T, 0, stream>>>(bsums, bsums, nullptr, nsb);
    scan_add<<<nsb, SCAN_T, 0, stream>>>(rs, bsums, N, E);
    prep2_k<<<nblk, 256, 0, stream>>>(cnt, batch, dinv, bh, gstart, N, G, nblk);
    scatter_k<<<(E + 255) / 256, 256, 0, stream>>>(src, dst, rs, cursor, dinv, cw, E);
    colsum_k<<<(E + N + 255) / 256, 256, 0, stream>>>(src, dst, batch, dinv, colsum, N, E);

    // counting-sort scan + scatter -> srt
    int nsb2 = (nbh + SCAN_E - 1) / SCAN_E;
    scan_block<<<nsb2, SCAN_T, 0, stream>>>(bh, bh, bsums, nbh);
    scan_block<<<1, SCAN_T, 0, stream>>>(bsums, bsums, nullptr, nsb2);
    scan_add<<<nsb2, SCAN_T, 0, stream>>>(bh, bsums, nbh, N);
    dorder3_k<<<nblk, 256, 0, stream>>>(cnt, batch, rs, dinv, bh, srt, N, nblk);

    // weight prep
    wprep_h<<<(L * INTER * INTER + 255) / 256, 256, 0, stream>>>(W_h, Wht, L);

    // input layer (fused aggregate + transform)
    agg_in_k<<<nblk, 256, 0, stream>>>(x, rs, cw, dinv, W_in, b_in, h, N);

    // hidden layers: first L-1 standard, last fused with pooling
    unsigned short* hin = h;
    unsigned short* hout = h2;
    for (int l = 0; l < L - 1; l++) {
        fused_hidden8<<<(N + 31) / 32, 256, 0, stream>>>(
            hin, cw, srt, Wht + (size_t)l * INTER * INTER, b_h + (size_t)l * INTER, hout, N);
        unsigned short* tmp = hin; hin = hout; hout = tmp;
    }
    fused_hidden_last<<<(N + 31) / 32, 256, 0, stream>>>(
        hin, cw, srt, Wht + (size_t)(L - 1) * INTER * INTER, b_h + (size_t)(L - 1) * INTER,
        colsum, gsum, N);

    // final: slot-sum, matmul with W_out (fp32), mean, bias, sigmoid
    final6_k<<<1, 512, 0, stream>>>(gsum, gstart, W_out, b_out, (float*)d_out);
}

// Round 18
// 461.737 us; speedup vs baseline: 1.1404x; 1.0514x over previous
//
#include <hip/hip_runtime.h>
#include <math.h>

// ---------------- constants ----------------
#define INTER 128
#define OUTD  64
#define SCAN_T 256
#define SCAN_E 1024
#define NBIN  256    // sort key bins: batch*32 + min(deg,31)
#define NSLOT 64

using bf16x8 = __attribute__((ext_vector_type(8))) short;
using f32x4  = __attribute__((ext_vector_type(4))) float;

static __device__ __forceinline__ unsigned short f2bf(float f) {
    unsigned int u = __float_as_uint(f);
    u += 0x7fffu + ((u >> 16) & 1u);          // RTNE
    return (unsigned short)(u >> 16);
}
static __device__ __forceinline__ unsigned int pk2(float a, float b) {
    return (unsigned int)f2bf(a) | ((unsigned int)f2bf(b) << 16);
}
static __device__ __forceinline__ float bflo(unsigned int u) { return __uint_as_float(u << 16); }
static __device__ __forceinline__ float bfhi(unsigned int u) { return __uint_as_float(u & 0xffff0000u); }

static __device__ __forceinline__ void fma8(float* a, float w, uint4 v) {
    a[0] = fmaf(w, bflo(v.x), a[0]); a[1] = fmaf(w, bfhi(v.x), a[1]);
    a[2] = fmaf(w, bflo(v.y), a[2]); a[3] = fmaf(w, bfhi(v.y), a[3]);
    a[4] = fmaf(w, bflo(v.z), a[4]); a[5] = fmaf(w, bfhi(v.z), a[5]);
    a[6] = fmaf(w, bflo(v.w), a[6]); a[7] = fmaf(w, bfhi(v.w), a[7]);
}
static __device__ __forceinline__ void seed8(float* a, float sn, uint4 v) {
    a[0] = sn * bflo(v.x); a[1] = sn * bfhi(v.x);
    a[2] = sn * bflo(v.y); a[3] = sn * bfhi(v.y);
    a[4] = sn * bflo(v.z); a[5] = sn * bfhi(v.z);
    a[6] = sn * bflo(v.w); a[7] = sn * bfhi(v.w);
}

// ---------------- CSR build ----------------
__global__ void count_k(const int* __restrict__ dst, int* __restrict__ cnt, int E) {
    int e = blockIdx.x * 256 + threadIdx.x;
    if (e < E) atomicAdd(&cnt[dst[e]], 1);
}

__global__ void scan_block(const int* __restrict__ in, int* __restrict__ out,
                           int* __restrict__ bsums, int n) {
    __shared__ int sh[SCAN_T];
    int base = blockIdx.x * SCAN_E;
    int t = threadIdx.x;
    int v[4];
    int s = 0;
#pragma unroll
    for (int i = 0; i < 4; i++) {
        int idx = base + t * 4 + i;
        v[i] = (idx < n) ? in[idx] : 0;
        s += v[i];
    }
    sh[t] = s;
    __syncthreads();
    for (int off = 1; off < SCAN_T; off <<= 1) {
        int x = (t >= off) ? sh[t - off] : 0;
        __syncthreads();
        sh[t] += x;
        __syncthreads();
    }
    int excl = (t == 0) ? 0 : sh[t - 1];
    if (bsums && t == SCAN_T - 1) bsums[blockIdx.x] = sh[t];
#pragma unroll
    for (int i = 0; i < 4; i++) {
        int idx = base + t * 4 + i;
        if (idx < n) out[idx] = excl;
        excl += v[i];
    }
}

__global__ void scan_add(int* __restrict__ out, const int* __restrict__ bsums, int n, int total) {
    int idx = blockIdx.x * SCAN_E + threadIdx.x * 4;
    int add = bsums[blockIdx.x];
#pragma unroll
    for (int i = 0; i < 4; i++) {
        int j = idx + i;
        if (j < n) out[j] += add;
    }
    if (blockIdx.x == 0 && threadIdx.x == 0) out[n] = total;
}

__global__ void scatter_k(const int* __restrict__ src, const int* __restrict__ dst,
                          const int* __restrict__ rs, int* __restrict__ cursor,
                          const float* __restrict__ dinv,
                          int2* __restrict__ cw, int E) {
    int e = blockIdx.x * 256 + threadIdx.x;
    if (e >= E) return;
    int s = src[e], d = dst[e];
    int pos = rs[d] + atomicAdd(&cursor[d], 1);
    cw[pos] = make_int2(s, __float_as_int(dinv[s] * dinv[d]));
}

// ---------------- fused prep: dinv + key-histogram + graph bounds ----------------
__global__ __launch_bounds__(256) void prep2_k(const int* __restrict__ cnt,
                                               const int* __restrict__ batch,
                                               float* __restrict__ dinv,
                                               int* __restrict__ blockhist,
                                               int* __restrict__ gstart,
                                               int N, int G, int nblk) {
    __shared__ int hist[NBIN];
    int t = threadIdx.x;
    if (t < NBIN) hist[t] = 0;
    __syncthreads();
    int i = blockIdx.x * 256 + t;
    if (i < N) {
        int d = cnt[i];
        dinv[i] = rsqrtf((float)(d + 1));
        int b = batch[i];
        atomicAdd(&hist[b * 32 + min(d, 31)], 1);
        int prev = (i == 0) ? -1 : batch[i - 1];
        for (int g2 = prev + 1; g2 <= b; g2++) gstart[g2] = i;
        if (i == N - 1) for (int g2 = b + 1; g2 <= G; g2++) gstart[g2] = N;
    }
    __syncthreads();
    if (t < NBIN) blockhist[t * nblk + blockIdx.x] = hist[t];
}

// scatter into sorted order; srt = (node, rs0, rs1, dinv_bits)
__global__ __launch_bounds__(256) void dorder3_k(const int* __restrict__ cnt,
                                                 const int* __restrict__ batch,
                                                 const int* __restrict__ rs,
                                                 const float* __restrict__ dinv,
                                                 const int* __restrict__ offs,
                                                 int4* __restrict__ srt,
                                                 int N, int nblk) {
    __shared__ int cur[NBIN];
    int t = threadIdx.x;
    if (t < NBIN) cur[t] = 0;
    __syncthreads();
    int i = blockIdx.x * 256 + t;
    if (i >= N) return;
    int key = batch[i] * 32 + min(cnt[i], 31);
    int r = atomicAdd(&cur[key], 1);              // LDS atomic, block-local
    int p = offs[key * nblk + blockIdx.x] + r;
    srt[p] = make_int4(i, rs[i], rs[i + 1], __float_as_int(dinv[i]));
}

// ---------------- weight prep (fp32 -> bf16, transposed [n][k]) ----------------
__global__ void wprep_h(const float* __restrict__ W, unsigned short* __restrict__ Wt, int L) {
    int tid = blockIdx.x * 256 + threadIdx.x;
    if (tid >= L * INTER * INTER) return;
    int l = tid / (INTER * INTER);
    int r = tid % (INTER * INTER);
    int n = r / INTER, k = r % INTER;
    Wt[tid] = f2bf(W[(size_t)l * INTER * INTER + (size_t)k * INTER + n]);
}

// ---------------- fused input layer: h = (A_hat x) @ W_in + b_in -> bf16 ----------------
__global__ __launch_bounds__(256) void agg_in_k(const float* __restrict__ x,
                                                const int* __restrict__ rs,
                                                const int2* __restrict__ cw,
                                                const float* __restrict__ dinv,
                                                const float* __restrict__ Wi,
                                                const float* __restrict__ bi,
                                                unsigned short* __restrict__ h, int N) {
    __shared__ float2 axs[256];
    int t = threadIdx.x;
    int i = blockIdx.x * 256 + t;
    float a0 = 0.f, a1 = 0.f;
    if (i < N) {
        float di = dinv[i];
        float sn = di * di;
        float2 xv = ((const float2*)x)[i];
        a0 = sn * xv.x; a1 = sn * xv.y;
        int e0 = rs[i], e1 = rs[i + 1];
        for (int k = e0; k < e1; k += 2) {
            int2 c0 = cw[k];
            int2 c1 = (k + 1 < e1) ? cw[k + 1] : make_int2(0, 0);
            float2 x0 = ((const float2*)x)[c0.x];
            float2 x1 = ((const float2*)x)[c1.x];
            float w0 = __int_as_float(c0.y), w1 = __int_as_float(c1.y);
            a0 = fmaf(w0, x0.x, a0); a1 = fmaf(w0, x0.y, a1);
            a0 = fmaf(w1, x1.x, a0); a1 = fmaf(w1, x1.y, a1);
        }
    }
    axs[t] = make_float2(a0, a1);
    __syncthreads();
    int base = blockIdx.x * 256;
#pragma unroll
    for (int p = 0; p < 16; p++) {
        int nl = p * 16 + (t >> 4);
        int nb = base + nl;
        if (nb < N) {
            int j0 = (t & 15) * 8;
            float2 a = axs[nl];
            float4 wa0 = *(const float4*)&Wi[j0];       float4 wa1 = *(const float4*)&Wi[j0 + 4];
            float4 wb0 = *(const float4*)&Wi[128 + j0]; float4 wb1 = *(const float4*)&Wi[128 + j0 + 4];
            float4 bb0 = *(const float4*)&bi[j0];       float4 bb1 = *(const float4*)&bi[j0 + 4];
            float h0 = fmaf(a.x, wa0.x, fmaf(a.y, wb0.x, bb0.x));
            float h1 = fmaf(a.x, wa0.y, fmaf(a.y, wb0.y, bb0.y));
            float h2 = fmaf(a.x, wa0.z, fmaf(a.y, wb0.z, bb0.z));
            float h3 = fmaf(a.x, wa0.w, fmaf(a.y, wb0.w, bb0.w));
            float h4 = fmaf(a.x, wa1.x, fmaf(a.y, wb1.x, bb1.x));
            float h5 = fmaf(a.x, wa1.y, fmaf(a.y, wb1.y, bb1.y));
            float h6 = fmaf(a.x, wa1.z, fmaf(a.y, wb1.z, bb1.z));
            float h7 = fmaf(a.x, wa1.w, fmaf(a.y, wb1.w, bb1.w));
            *(uint4*)(h + (size_t)nb * 128 + j0) =
                make_uint4(pk2(h0, h1), pk2(h2, h3), pk2(h4, h5), pk2(h6, h7));
        }
    }
}

// ---------------- fused hidden layer (layers 0..L-2): Hout = relu((A_hat Hin) W + b) ----------------
__global__ __launch_bounds__(256) void fused_hidden8(
    const unsigned short* __restrict__ Hin,
    const int2* __restrict__ cw,
    const int4* __restrict__ srt,
    const unsigned short* __restrict__ Wt,   // [128][128] bf16, Wt[n][k] = W[k][n]
    const float* __restrict__ bias,
    unsigned short* __restrict__ Hout, int N)
{
    __shared__ __align__(16) unsigned short T[32][136];
    __shared__ int nodeid[32];
    const int t = threadIdx.x;
    const int q = t & 15;        // 16 lanes per node
    const int gi = t >> 4;       // 0..15
    const int sA = blockIdx.x * 32 + gi;
    const int sB = sA + 16;
    int4 dA = (sA < N) ? srt[sA] : make_int4(-1, 0, 0, 0);
    int4 dB = (sB < N) ? srt[sB] : make_int4(-1, 0, 0, 0);
    if (q == 0) {
        nodeid[gi]      = dA.x;
        nodeid[gi + 16] = dB.x;
    }

    float accA[8] = {0,0,0,0,0,0,0,0}, accB[8] = {0,0,0,0,0,0,0,0};
    int kA = 0, eA = 0, kB = 0, eB = 0;
    if (dA.x >= 0) {
        float dv = __int_as_float(dA.w);
        seed8(accA, dv * dv, *(const uint4*)(Hin + (size_t)dA.x * 128 + q * 8));
        kA = dA.y; eA = dA.z;
    }
    if (dB.x >= 0) {
        float dv = __int_as_float(dB.w);
        seed8(accB, dv * dv, *(const uint4*)(Hin + (size_t)dB.x * 128 + q * 8));
        kB = dB.y; eB = dB.z;
    }

    while (kA < eA || kB < eB) {
        int2 cA0 = (kA     < eA) ? cw[kA]     : make_int2(0, 0);
        int2 cA1 = (kA + 1 < eA) ? cw[kA + 1] : make_int2(0, 0);
        int2 cA2 = (kA + 2 < eA) ? cw[kA + 2] : make_int2(0, 0);
        int2 cA3 = (kA + 3 < eA) ? cw[kA + 3] : make_int2(0, 0);
        int2 cB0 = (kB     < eB) ? cw[kB]     : make_int2(0, 0);
        int2 cB1 = (kB + 1 < eB) ? cw[kB + 1] : make_int2(0, 0);
        int2 cB2 = (kB + 2 < eB) ? cw[kB + 2] : make_int2(0, 0);
        int2 cB3 = (kB + 3 < eB) ? cw[kB + 3] : make_int2(0, 0);
        uint4 vA0 = *(const uint4*)(Hin + (size_t)cA0.x * 128 + q * 8);
        uint4 vA1 = *(const uint4*)(Hin + (size_t)cA1.x * 128 + q * 8);
        uint4 vA2 = *(const uint4*)(Hin + (size_t)cA2.x * 128 + q * 8);
        uint4 vA3 = *(const uint4*)(Hin + (size_t)cA3.x * 128 + q * 8);
        uint4 vB0 = *(const uint4*)(Hin + (size_t)cB0.x * 128 + q * 8);
        uint4 vB1 = *(const uint4*)(Hin + (size_t)cB1.x * 128 + q * 8);
        uint4 vB2 = *(const uint4*)(Hin + (size_t)cB2.x * 128 + q * 8);
        uint4 vB3 = *(const uint4*)(Hin + (size_t)cB3.x * 128 + q * 8);
        fma8(accA, __int_as_float(cA0.y), vA0);
        fma8(accA, __int_as_float(cA1.y), vA1);
        fma8(accA, __int_as_float(cA2.y), vA2);
        fma8(accA, __int_as_float(cA3.y), vA3);
        fma8(accB, __int_as_float(cB0.y), vB0);
        fma8(accB, __int_as_float(cB1.y), vB1);
        fma8(accB, __int_as_float(cB2.y), vB2);
        fma8(accB, __int_as_float(cB3.y), vB3);
        kA += 4; kB += 4;
    }

    {
        uint4 oA = make_uint4(pk2(accA[0], accA[1]), pk2(accA[2], accA[3]),
                              pk2(accA[4], accA[5]), pk2(accA[6], accA[7]));
        uint4 oB = make_uint4(pk2(accB[0], accB[1]), pk2(accB[2], accB[3]),
                              pk2(accB[4], accB[5]), pk2(accB[6], accB[7]));
        *(uint4*)&T[gi][q * 8] = oA;
        *(uint4*)&T[gi + 16][q * 8] = oB;
    }
    __syncthreads();

    // phase 2: MFMA from T
    const int wv = t >> 6;       // wave -> col slice [wv*32, wv*32+32)
    const int lane = t & 63;
    const int r15 = lane & 15;
    const int kg = lane >> 4;

    bf16x8 bfr[2][4];
#pragma unroll
    for (int nc = 0; nc < 2; nc++)
#pragma unroll
        for (int ks = 0; ks < 4; ks++)
            bfr[nc][ks] = *(const bf16x8*)&T[nc * 16 + r15][kg * 8 + ks * 32];

    f32x4 acc[2][2];
#pragma unroll
    for (int nc = 0; nc < 2; nc++)
#pragma unroll
        for (int c = 0; c < 2; c++) acc[nc][c] = (f32x4){0.f, 0.f, 0.f, 0.f};

#pragma unroll
    for (int c = 0; c < 2; c++) {
        const unsigned short* wrow = Wt + (size_t)(wv * 32 + c * 16 + r15) * 128 + kg * 8;
#pragma unroll
        for (int ks = 0; ks < 4; ks++) {
            bf16x8 afr = *(const bf16x8*)(wrow + ks * 32);
            acc[0][c] = __builtin_amdgcn_mfma_f32_16x16x32_bf16(afr, bfr[0][ks], acc[0][c], 0, 0, 0);
            acc[1][c] = __builtin_amdgcn_mfma_f32_16x16x32_bf16(afr, bfr[1][ks], acc[1][c], 0, 0, 0);
        }
    }
    __syncthreads();   // all waves done reading T; safe to overwrite

    // bias+relu, stage results into T[node_local][col]
#pragma unroll
    for (int nc = 0; nc < 2; nc++) {
#pragma unroll
        for (int c = 0; c < 2; c++) {
            int col = wv * 32 + c * 16 + kg * 4;
            float4 bv = *(const float4*)(bias + col);
            float v0 = fmaxf(acc[nc][c][0] + bv.x, 0.f);
            float v1 = fmaxf(acc[nc][c][1] + bv.y, 0.f);
            float v2 = fmaxf(acc[nc][c][2] + bv.z, 0.f);
            float v3 = fmaxf(acc[nc][c][3] + bv.w, 0.f);
            *(uint2*)&T[nc * 16 + r15][col] = make_uint2(pk2(v0, v1), pk2(v2, v3));
        }
    }
    __syncthreads();

    // cooperative full-line stores: 16 lanes x 16B = one 256B row per group
#pragma unroll
    for (int p = 0; p < 2; p++) {
        int row = p * 16 + gi;
        int node = nodeid[row];
        if (node >= 0) {
            *(uint4*)(Hout + (size_t)node * 128 + q * 8) = *(const uint4*)&T[row][q * 8];
        }
    }
}

// ---------------- last hidden layer + pooling (csT staged in LDS) ----------------
__global__ __launch_bounds__(256) void fused_hidden_last(
    const unsigned short* __restrict__ Hin,
    const int2* __restrict__ cw,
    const int4* __restrict__ srt,
    const unsigned short* __restrict__ Wt,
    const float* __restrict__ bias,
    const float* __restrict__ csT,      // [N][8] node-major colsum
    float* __restrict__ gsum,           // [NSLOT][8][128]
    int N)
{
    __shared__ __align__(16) unsigned short T[32][136];
    __shared__ int nodeid[32];
    __shared__ float cs[32][8];
    __shared__ float P[2][8][128];
    const int t = threadIdx.x;
    const int q = t & 15;
    const int gi = t >> 4;
    const int sA = blockIdx.x * 32 + gi;
    const int sB = sA + 16;
    int4 dA = (sA < N) ? srt[sA] : make_int4(-1, 0, 0, 0);
    int4 dB = (sB < N) ? srt[sB] : make_int4(-1, 0, 0, 0);
    if (q == 0) {
        nodeid[gi]      = dA.x;
        nodeid[gi + 16] = dB.x;
    }
    // stage csT rows for this block's nodes (q=0/1 lanes: 2 uint4 per node)
    if (q < 2) {
        const float* srcp0 = (dA.x >= 0) ? &csT[(size_t)dA.x * 8 + q * 4] : nullptr;
        const float* srcp1 = (dB.x >= 0) ? &csT[(size_t)dB.x * 8 + q * 4] : nullptr;
        float4 z = make_float4(0.f, 0.f, 0.f, 0.f);
        *(float4*)&cs[gi][q * 4]      = srcp0 ? *(const float4*)srcp0 : z;
        *(float4*)&cs[gi + 16][q * 4] = srcp1 ? *(const float4*)srcp1 : z;
    }

    float accA[8] = {0,0,0,0,0,0,0,0}, accB[8] = {0,0,0,0,0,0,0,0};
    int kA = 0, eA = 0, kB = 0, eB = 0;
    if (dA.x >= 0) {
        float dv = __int_as_float(dA.w);
        seed8(accA, dv * dv, *(const uint4*)(Hin + (size_t)dA.x * 128 + q * 8));
        kA = dA.y; eA = dA.z;
    }
    if (dB.x >= 0) {
        float dv = __int_as_float(dB.w);
        seed8(accB, dv * dv, *(const uint4*)(Hin + (size_t)dB.x * 128 + q * 8));
        kB = dB.y; eB = dB.z;
    }

    while (kA < eA || kB < eB) {
        int2 cA0 = (kA     < eA) ? cw[kA]     : make_int2(0, 0);
        int2 cA1 = (kA + 1 < eA) ? cw[kA + 1] : make_int2(0, 0);
        int2 cA2 = (kA + 2 < eA) ? cw[kA + 2] : make_int2(0, 0);
        int2 cA3 = (kA + 3 < eA) ? cw[kA + 3] : make_int2(0, 0);
        int2 cB0 = (kB     < eB) ? cw[kB]     : make_int2(0, 0);
        int2 cB1 = (kB + 1 < eB) ? cw[kB + 1] : make_int2(0, 0);
        int2 cB2 = (kB + 2 < eB) ? cw[kB + 2] : make_int2(0, 0);
        int2 cB3 = (kB + 3 < eB) ? cw[kB + 3] : make_int2(0, 0);
        uint4 vA0 = *(const uint4*)(Hin + (size_t)cA0.x * 128 + q * 8);
        uint4 vA1 = *(const uint4*)(Hin + (size_t)cA1.x * 128 + q * 8);
        uint4 vA2 = *(const uint4*)(Hin + (size_t)cA2.x * 128 + q * 8);
        uint4 vA3 = *(const uint4*)(Hin + (size_t)cA3.x * 128 + q * 8);
        uint4 vB0 = *(const uint4*)(Hin + (size_t)cB0.x * 128 + q * 8);
        uint4 vB1 = *(const uint4*)(Hin + (size_t)cB1.x * 128 + q * 8);
        uint4 vB2 = *(const uint4*)(Hin + (size_t)cB2.x * 128 + q * 8);
        uint4 vB3 = *(const uint4*)(Hin + (size_t)cB3.x * 128 + q * 8);
        fma8(accA, __int_as_float(cA0.y), vA0);
        fma8(accA, __int_as_float(cA1.y), vA1);
        fma8(accA, __int_as_float(cA2.y), vA2);
        fma8(accA, __int_as_float(cA3.y), vA3);
        fma8(accB, __int_as_float(cB0.y), vB0);
        fma8(accB, __int_as_float(cB1.y), vB1);
        fma8(accB, __int_as_float(cB2.y), vB2);
        fma8(accB, __int_as_float(cB3.y), vB3);
        kA += 4; kB += 4;
    }

    {
        uint4 oA = make_uint4(pk2(accA[0], accA[1]), pk2(accA[2], accA[3]),
                              pk2(accA[4], accA[5]), pk2(accA[6], accA[7]));
        uint4 oB = make_uint4(pk2(accB[0], accB[1]), pk2(accB[2], accB[3]),
                              pk2(accB[4], accB[5]), pk2(accB[6], accB[7]));
        *(uint4*)&T[gi][q * 8] = oA;
        *(uint4*)&T[gi + 16][q * 8] = oB;
    }
    __syncthreads();

    const int wv = t >> 6;
    const int lane = t & 63;
    const int r15 = lane & 15;
    const int kg = lane >> 4;

    bf16x8 bfr[2][4];
#pragma unroll
    for (int nc = 0; nc < 2; nc++)
#pragma unroll
        for (int ks = 0; ks < 4; ks++)
            bfr[nc][ks] = *(const bf16x8*)&T[nc * 16 + r15][kg * 8 + ks * 32];

    f32x4 acc[2][2];
#pragma unroll
    for (int nc = 0; nc < 2; nc++)
#pragma unroll
        for (int c = 0; c < 2; c++) acc[nc][c] = (f32x4){0.f, 0.f, 0.f, 0.f};

#pragma unroll
    for (int c = 0; c < 2; c++) {
        const unsigned short* wrow = Wt + (size_t)(wv * 32 + c * 16 + r15) * 128 + kg * 8;
#pragma unroll
        for (int ks = 0; ks < 4; ks++) {
            bf16x8 afr = *(const bf16x8*)(wrow + ks * 32);
            acc[0][c] = __builtin_amdgcn_mfma_f32_16x16x32_bf16(afr, bfr[0][ks], acc[0][c], 0, 0, 0);
            acc[1][c] = __builtin_amdgcn_mfma_f32_16x16x32_bf16(afr, bfr[1][ks], acc[1][c], 0, 0, 0);
        }
    }
    __syncthreads();

    // bias+relu, stage h4 rows into T
#pragma unroll
    for (int nc = 0; nc < 2; nc++) {
#pragma unroll
        for (int c = 0; c < 2; c++) {
            int col = wv * 32 + c * 16 + kg * 4;
            float4 bv = *(const float4*)(bias + col);
            float v0 = fmaxf(acc[nc][c][0] + bv.x, 0.f);
            float v1 = fmaxf(acc[nc][c][1] + bv.y, 0.f);
            float v2 = fmaxf(acc[nc][c][2] + bv.z, 0.f);
            float v3 = fmaxf(acc[nc][c][3] + bv.w, 0.f);
            *(uint2*)&T[nc * 16 + r15][col] = make_uint2(pk2(v0, v1), pk2(v2, v3));
        }
    }
    __syncthreads();

    // pooling epilogue: thread (f, half) accumulates 16 rows x 8 graphs from LDS cs
    {
        const int f = t & 127;
        const int half = t >> 7;
        float pacc[8] = {0,0,0,0,0,0,0,0};
        for (int r = 0; r < 16; r++) {
            int row = half * 16 + r;
            float val = bflo((unsigned int)T[row][f]);
#pragma unroll
            for (int g = 0; g < 8; g++)
                pacc[g] = fmaf(cs[row][g], val, pacc[g]);
        }
#pragma unroll
        for (int g = 0; g < 8; g++) P[half][g][f] = pacc[g];
        __syncthreads();
        if (half == 0) {
            int slot = blockIdx.x & (NSLOT - 1);
#pragma unroll
            for (int g = 0; g < 8; g++)
                atomicAdd(&gsum[((size_t)slot * 8 + g) * 128 + f], P[0][g][f] + P[1][g][f]);
        }
    }
}

// ---------------- colsum transposed: csT[j][g] = sum_{i in g} A_hat_ij ----------------
__global__ void colsumT_k(const int* __restrict__ src, const int* __restrict__ dst,
                          const int* __restrict__ batch, const float* __restrict__ dinv,
                          float* __restrict__ csT, int N, int E) {
    int e = blockIdx.x * 256 + threadIdx.x;
    if (e < E) {
        int s = src[e], d = dst[e];
        atomicAdd(&csT[(size_t)s * 8 + batch[d]], dinv[s] * dinv[d]);
    } else if (e < E + N) {
        int i = e - E;
        float di = dinv[i];
        atomicAdd(&csT[(size_t)i * 8 + batch[i]], di * di);
    }
}

// ---------------- final: sg = sum slots; out = sigmoid(sg @ W_out / c + b) ----------------
__global__ void final6_k(const float* __restrict__ gsum, const int* __restrict__ gstart,
                         const float* __restrict__ W_out, const float* __restrict__ b_out,
                         float* __restrict__ out) {
    __shared__ float sg[8][128];
    int t = threadIdx.x;  // 512
    for (int i = t; i < 1024; i += 512) {
        int g = i >> 7, k = i & 127;
        float s = 0.f;
        for (int sl = 0; sl < NSLOT; sl++) s += gsum[((size_t)sl * 8 + g) * 128 + k];
        sg[g][k] = s;
    }
    __syncthreads();
    int g = t / 64, f = t % 64;
    float dot = 0.f;
    for (int k = 0; k < 128; k++) dot = fmaf(sg[g][k], W_out[k * 64 + f], dot);
    int c = gstart[g + 1] - gstart[g];
    float v = dot / (float)max(c, 1) + b_out[f];
    out[g * 64 + f] = 1.f / (1.f + expf(-v));
}

// ---------------- launch ----------------
extern "C" void kernel_launch(void* const* d_in, const int* in_sizes, int n_in,
                              void* d_out, int out_size, void* d_ws, size_t ws_size,
                              hipStream_t stream) {
    const float* x     = (const float*)d_in[0];
    const int*   ei    = (const int*)d_in[1];
    const int*   batch = (const int*)d_in[2];
    const float* W_in  = (const float*)d_in[3];
    const float* b_in  = (const float*)d_in[4];
    const float* W_h   = (const float*)d_in[5];
    const float* b_h   = (const float*)d_in[6];
    const float* W_out = (const float*)d_in[7];
    const float* b_out = (const float*)d_in[8];

    const int N = in_sizes[2];
    const int E = in_sizes[1] / 2;
    const int L = in_sizes[5] / (INTER * INTER);
    const int G = 8;
    const int* src = ei;
    const int* dst = ei + E;
    const int nblk = (N + 255) / 256;
    const int nbh = NBIN * nblk;              // blockhist size

    char* ws = (char*)d_ws;
    size_t off = 0;
    auto alloc = [&](size_t bytes) -> void* {
        void* p = ws + off;
        off += (bytes + 255) & ~(size_t)255;
        return p;
    };
    int*   cnt    = (int*)alloc((size_t)N * 4);
    int*   cursor = (int*)alloc((size_t)N * 4);   // adjacent to cnt: one memset covers both
    int*   rs     = (int*)alloc((size_t)(N + 1) * 4);
    int*   bsums  = (int*)alloc(4096);
    float* dinv   = (float*)alloc((size_t)N * 4);
    int2*  cw     = (int2*)alloc((size_t)E * 8);
    unsigned short* h   = (unsigned short*)alloc((size_t)N * INTER * 2);
    unsigned short* h2  = (unsigned short*)alloc((size_t)N * INTER * 2);
    unsigned short* Wht = (unsigned short*)alloc((size_t)L * INTER * INTER * 2);
    float* csT    = (float*)alloc((size_t)N * 8 * 4);
    float* gsum   = (float*)alloc((size_t)NSLOT * 8 * 128 * 4);
    int*   gstart = (int*)alloc((G + 1) * 4);
    int*   bh     = (int*)alloc((size_t)(nbh + 1) * 4);
    int4*  srt    = (int4*)alloc((size_t)N * 16);
    (void)ws_size; (void)n_in;

    hipMemsetAsync(cnt, 0, (size_t)N * 8, stream);   // cnt + cursor (adjacent)
    hipMemsetAsync(csT, 0, (size_t)N * 8 * 4, stream);
    hipMemsetAsync(gsum, 0, (size_t)NSLOT * 8 * 128 * 4, stream);

    // CSR build
    count_k<<<(E + 255) / 256, 256, 0, stream>>>(dst, cnt, E);
    int nsb = (N + SCAN_E - 1) / SCAN_E;
    scan_block<<<nsb, SCAN_T, 0, stream>>>(cnt, rs, bsums, N);
    scan_block<<<1, SCAN_T, 0, stream>>>(bsums, bsums, nullptr, nsb);
    scan_add<<<nsb, SCAN_T, 0, stream>>>(rs, bsums, N, E);
    prep2_k<<<nblk, 256, 0, stream>>>(cnt, batch, dinv, bh, gstart, N, G, nblk);
    scatter_k<<<(E + 255) / 256, 256, 0, stream>>>(src, dst, rs, cursor, dinv, cw, E);
    colsumT_k<<<(E + N + 255) / 256, 256, 0, stream>>>(src, dst, batch, dinv, csT, N, E);

    // counting-sort scan + scatter -> srt
    int nsb2 = (nbh + SCAN_E - 1) / SCAN_E;
    scan_block<<<nsb2, SCAN_T, 0, stream>>>(bh, bh, bsums, nbh);
    scan_block<<<1, SCAN_T, 0, stream>>>(bsums, bsums, nullptr, nsb2);
    scan_add<<<nsb2, SCAN_T, 0, stream>>>(bh, bsums, nbh, N);
    dorder3_k<<<nblk, 256, 0, stream>>>(cnt, batch, rs, dinv, bh, srt, N, nblk);

    // weight prep
    wprep_h<<<(L * INTER * INTER + 255) / 256, 256, 0, stream>>>(W_h, Wht, L);

    // input layer (fused aggregate + transform)
    agg_in_k<<<nblk, 256, 0, stream>>>(x, rs, cw, dinv, W_in, b_in, h, N);

    // hidden layers: first L-1 standard, last fused with pooling
    unsigned short* hin = h;
    unsigned short* hout = h2;
    for (int l = 0; l < L - 1; l++) {
        fused_hidden8<<<(N + 31) / 32, 256, 0, stream>>>(
            hin, cw, srt, Wht + (size_t)l * INTER * INTER, b_h + (size_t)l * INTER, hout, N);
        unsigned short* tmp = hin; hin = hout; hout = tmp;
    }
    fused_hidden_last<<<(N + 31) / 32, 256, 0, stream>>>(
        hin, cw, srt, Wht + (size_t)(L - 1) * INTER * INTER, b_h + (size_t)(L - 1) * INTER,
        csT, gsum, N);

    // final: slot-sum, matmul with W_out (fp32), mean, bias, sigmoid
    final6_k<<<1, 512, 0, stream>>>(gsum, gstart, W_out, b_out, (float*)d_out);
}

// Round 19
// 461.453 us; speedup vs baseline: 1.1411x; 1.0006x over previous
//
#include <hip/hip_runtime.h>
#include <math.h>

// ---------------- constants ----------------
#define INTER 128
#define OUTD  64
#define SCAN_T 256
#define SCAN_E 1024
#define NBIN  256    // sort key bins: batch*32 + min(deg,31)
#define NSLOT 64
#define NXCD  8

using bf16x8 = __attribute__((ext_vector_type(8))) short;
using f32x4  = __attribute__((ext_vector_type(4))) float;

static __device__ __forceinline__ unsigned short f2bf(float f) {
    unsigned int u = __float_as_uint(f);
    u += 0x7fffu + ((u >> 16) & 1u);          // RTNE
    return (unsigned short)(u >> 16);
}
static __device__ __forceinline__ unsigned int pk2(float a, float b) {
    return (unsigned int)f2bf(a) | ((unsigned int)f2bf(b) << 16);
}
static __device__ __forceinline__ float bflo(unsigned int u) { return __uint_as_float(u << 16); }
static __device__ __forceinline__ float bfhi(unsigned int u) { return __uint_as_float(u & 0xffff0000u); }

// XCD-affinity swizzle: give each XCD a contiguous chunk of blocks
// (batch-major srt => contiguous blocks = one graph = one 6.4MB row region).
static __device__ __forceinline__ int xcd_swizzle(int bid, int nwg) {
    int cpx = nwg / NXCD;
    if (bid < cpx * NXCD) return (bid % NXCD) * cpx + bid / NXCD;
    return bid;
}

static __device__ __forceinline__ void fma8(float* a, float w, uint4 v) {
    a[0] = fmaf(w, bflo(v.x), a[0]); a[1] = fmaf(w, bfhi(v.x), a[1]);
    a[2] = fmaf(w, bflo(v.y), a[2]); a[3] = fmaf(w, bfhi(v.y), a[3]);
    a[4] = fmaf(w, bflo(v.z), a[4]); a[5] = fmaf(w, bfhi(v.z), a[5]);
    a[6] = fmaf(w, bflo(v.w), a[6]); a[7] = fmaf(w, bfhi(v.w), a[7]);
}
static __device__ __forceinline__ void seed8(float* a, float sn, uint4 v) {
    a[0] = sn * bflo(v.x); a[1] = sn * bfhi(v.x);
    a[2] = sn * bflo(v.y); a[3] = sn * bfhi(v.y);
    a[4] = sn * bflo(v.z); a[5] = sn * bfhi(v.z);
    a[6] = sn * bflo(v.w); a[7] = sn * bfhi(v.w);
}

// ---------------- CSR build ----------------
__global__ void count_k(const int* __restrict__ dst, int* __restrict__ cnt, int E) {
    int e = blockIdx.x * 256 + threadIdx.x;
    if (e < E) atomicAdd(&cnt[dst[e]], 1);
}

__global__ void scan_block(const int* __restrict__ in, int* __restrict__ out,
                           int* __restrict__ bsums, int n) {
    __shared__ int sh[SCAN_T];
    int base = blockIdx.x * SCAN_E;
    int t = threadIdx.x;
    int v[4];
    int s = 0;
#pragma unroll
    for (int i = 0; i < 4; i++) {
        int idx = base + t * 4 + i;
        v[i] = (idx < n) ? in[idx] : 0;
        s += v[i];
    }
    sh[t] = s;
    __syncthreads();
    for (int off = 1; off < SCAN_T; off <<= 1) {
        int x = (t >= off) ? sh[t - off] : 0;
        __syncthreads();
        sh[t] += x;
        __syncthreads();
    }
    int excl = (t == 0) ? 0 : sh[t - 1];
    if (bsums && t == SCAN_T - 1) bsums[blockIdx.x] = sh[t];
#pragma unroll
    for (int i = 0; i < 4; i++) {
        int idx = base + t * 4 + i;
        if (idx < n) out[idx] = excl;
        excl += v[i];
    }
}

__global__ void scan_add(int* __restrict__ out, const int* __restrict__ bsums, int n, int total) {
    int idx = blockIdx.x * SCAN_E + threadIdx.x * 4;
    int add = bsums[blockIdx.x];
#pragma unroll
    for (int i = 0; i < 4; i++) {
        int j = idx + i;
        if (j < n) out[j] += add;
    }
    if (blockIdx.x == 0 && threadIdx.x == 0) out[n] = total;
}

__global__ void scatter_k(const int* __restrict__ src, const int* __restrict__ dst,
                          const int* __restrict__ rs, int* __restrict__ cursor,
                          const float* __restrict__ dinv,
                          int2* __restrict__ cw, int E) {
    int e = blockIdx.x * 256 + threadIdx.x;
    if (e >= E) return;
    int s = src[e], d = dst[e];
    int pos = rs[d] + atomicAdd(&cursor[d], 1);
    cw[pos] = make_int2(s, __float_as_int(dinv[s] * dinv[d]));
}

// ---------------- fused prep: dinv + key-histogram + graph bounds ----------------
__global__ __launch_bounds__(256) void prep2_k(const int* __restrict__ cnt,
                                               const int* __restrict__ batch,
                                               float* __restrict__ dinv,
                                               int* __restrict__ blockhist,
                                               int* __restrict__ gstart,
                                               int N, int G, int nblk) {
    __shared__ int hist[NBIN];
    int t = threadIdx.x;
    if (t < NBIN) hist[t] = 0;
    __syncthreads();
    int i = blockIdx.x * 256 + t;
    if (i < N) {
        int d = cnt[i];
        dinv[i] = rsqrtf((float)(d + 1));
        int b = batch[i];
        atomicAdd(&hist[b * 32 + min(d, 31)], 1);
        int prev = (i == 0) ? -1 : batch[i - 1];
        for (int g2 = prev + 1; g2 <= b; g2++) gstart[g2] = i;
        if (i == N - 1) for (int g2 = b + 1; g2 <= G; g2++) gstart[g2] = N;
    }
    __syncthreads();
    if (t < NBIN) blockhist[t * nblk + blockIdx.x] = hist[t];
}

// scatter into sorted order; srt = (node, rs0, rs1, dinv_bits)
__global__ __launch_bounds__(256) void dorder3_k(const int* __restrict__ cnt,
                                                 const int* __restrict__ batch,
                                                 const int* __restrict__ rs,
                                                 const float* __restrict__ dinv,
                                                 const int* __restrict__ offs,
                                                 int4* __restrict__ srt,
                                                 int N, int nblk) {
    __shared__ int cur[NBIN];
    int t = threadIdx.x;
    if (t < NBIN) cur[t] = 0;
    __syncthreads();
    int i = blockIdx.x * 256 + t;
    if (i >= N) return;
    int key = batch[i] * 32 + min(cnt[i], 31);
    int r = atomicAdd(&cur[key], 1);              // LDS atomic, block-local
    int p = offs[key * nblk + blockIdx.x] + r;
    srt[p] = make_int4(i, rs[i], rs[i + 1], __float_as_int(dinv[i]));
}

// ---------------- weight prep (fp32 -> bf16, transposed [n][k]) ----------------
__global__ void wprep_h(const float* __restrict__ W, unsigned short* __restrict__ Wt, int L) {
    int tid = blockIdx.x * 256 + threadIdx.x;
    if (tid >= L * INTER * INTER) return;
    int l = tid / (INTER * INTER);
    int r = tid % (INTER * INTER);
    int n = r / INTER, k = r % INTER;
    Wt[tid] = f2bf(W[(size_t)l * INTER * INTER + (size_t)k * INTER + n]);
}

// ---------------- fused input layer: h = (A_hat x) @ W_in + b_in -> bf16 ----------------
__global__ __launch_bounds__(256) void agg_in_k(const float* __restrict__ x,
                                                const int* __restrict__ rs,
                                                const int2* __restrict__ cw,
                                                const float* __restrict__ dinv,
                                                const float* __restrict__ Wi,
                                                const float* __restrict__ bi,
                                                unsigned short* __restrict__ h, int N) {
    __shared__ float2 axs[256];
    int t = threadIdx.x;
    int i = blockIdx.x * 256 + t;
    float a0 = 0.f, a1 = 0.f;
    if (i < N) {
        float di = dinv[i];
        float sn = di * di;
        float2 xv = ((const float2*)x)[i];
        a0 = sn * xv.x; a1 = sn * xv.y;
        int e0 = rs[i], e1 = rs[i + 1];
        for (int k = e0; k < e1; k += 2) {
            int2 c0 = cw[k];
            int2 c1 = (k + 1 < e1) ? cw[k + 1] : make_int2(0, 0);
            float2 x0 = ((const float2*)x)[c0.x];
            float2 x1 = ((const float2*)x)[c1.x];
            float w0 = __int_as_float(c0.y), w1 = __int_as_float(c1.y);
            a0 = fmaf(w0, x0.x, a0); a1 = fmaf(w0, x0.y, a1);
            a0 = fmaf(w1, x1.x, a0); a1 = fmaf(w1, x1.y, a1);
        }
    }
    axs[t] = make_float2(a0, a1);
    __syncthreads();
    int base = blockIdx.x * 256;
#pragma unroll
    for (int p = 0; p < 16; p++) {
        int nl = p * 16 + (t >> 4);
        int nb = base + nl;
        if (nb < N) {
            int j0 = (t & 15) * 8;
            float2 a = axs[nl];
            float4 wa0 = *(const float4*)&Wi[j0];       float4 wa1 = *(const float4*)&Wi[j0 + 4];
            float4 wb0 = *(const float4*)&Wi[128 + j0]; float4 wb1 = *(const float4*)&Wi[128 + j0 + 4];
            float4 bb0 = *(const float4*)&bi[j0];       float4 bb1 = *(const float4*)&bi[j0 + 4];
            float h0 = fmaf(a.x, wa0.x, fmaf(a.y, wb0.x, bb0.x));
            float h1 = fmaf(a.x, wa0.y, fmaf(a.y, wb0.y, bb0.y));
            float h2 = fmaf(a.x, wa0.z, fmaf(a.y, wb0.z, bb0.z));
            float h3 = fmaf(a.x, wa0.w, fmaf(a.y, wb0.w, bb0.w));
            float h4 = fmaf(a.x, wa1.x, fmaf(a.y, wb1.x, bb1.x));
            float h5 = fmaf(a.x, wa1.y, fmaf(a.y, wb1.y, bb1.y));
            float h6 = fmaf(a.x, wa1.z, fmaf(a.y, wb1.z, bb1.z));
            float h7 = fmaf(a.x, wa1.w, fmaf(a.y, wb1.w, bb1.w));
            *(uint4*)(h + (size_t)nb * 128 + j0) =
                make_uint4(pk2(h0, h1), pk2(h2, h3), pk2(h4, h5), pk2(h6, h7));
        }
    }
}

// ---------------- fused hidden layer (layers 0..L-2): Hout = relu((A_hat Hin) W + b) ----------------
__global__ __launch_bounds__(256) void fused_hidden8(
    const unsigned short* __restrict__ Hin,
    const int2* __restrict__ cw,
    const int4* __restrict__ srt,
    const unsigned short* __restrict__ Wt,   // [128][128] bf16, Wt[n][k] = W[k][n]
    const float* __restrict__ bias,
    unsigned short* __restrict__ Hout, int N)
{
    __shared__ __align__(16) unsigned short T[32][136];
    __shared__ int nodeid[32];
    const int t = threadIdx.x;
    const int q = t & 15;        // 16 lanes per node
    const int gi = t >> 4;       // 0..15
    const int sbid = xcd_swizzle(blockIdx.x, gridDim.x);
    const int sA = sbid * 32 + gi;
    const int sB = sA + 16;
    int4 dA = (sA < N) ? srt[sA] : make_int4(-1, 0, 0, 0);
    int4 dB = (sB < N) ? srt[sB] : make_int4(-1, 0, 0, 0);
    if (q == 0) {
        nodeid[gi]      = dA.x;
        nodeid[gi + 16] = dB.x;
    }

    float accA[8] = {0,0,0,0,0,0,0,0}, accB[8] = {0,0,0,0,0,0,0,0};
    int kA = 0, eA = 0, kB = 0, eB = 0;
    if (dA.x >= 0) {
        float dv = __int_as_float(dA.w);
        seed8(accA, dv * dv, *(const uint4*)(Hin + (size_t)dA.x * 128 + q * 8));
        kA = dA.y; eA = dA.z;
    }
    if (dB.x >= 0) {
        float dv = __int_as_float(dB.w);
        seed8(accB, dv * dv, *(const uint4*)(Hin + (size_t)dB.x * 128 + q * 8));
        kB = dB.y; eB = dB.z;
    }

    while (kA < eA || kB < eB) {
        int2 cA0 = (kA     < eA) ? cw[kA]     : make_int2(0, 0);
        int2 cA1 = (kA + 1 < eA) ? cw[kA + 1] : make_int2(0, 0);
        int2 cA2 = (kA + 2 < eA) ? cw[kA + 2] : make_int2(0, 0);
        int2 cA3 = (kA + 3 < eA) ? cw[kA + 3] : make_int2(0, 0);
        int2 cB0 = (kB     < eB) ? cw[kB]     : make_int2(0, 0);
        int2 cB1 = (kB + 1 < eB) ? cw[kB + 1] : make_int2(0, 0);
        int2 cB2 = (kB + 2 < eB) ? cw[kB + 2] : make_int2(0, 0);
        int2 cB3 = (kB + 3 < eB) ? cw[kB + 3] : make_int2(0, 0);
        uint4 vA0 = *(const uint4*)(Hin + (size_t)cA0.x * 128 + q * 8);
        uint4 vA1 = *(const uint4*)(Hin + (size_t)cA1.x * 128 + q * 8);
        uint4 vA2 = *(const uint4*)(Hin + (size_t)cA2.x * 128 + q * 8);
        uint4 vA3 = *(const uint4*)(Hin + (size_t)cA3.x * 128 + q * 8);
        uint4 vB0 = *(const uint4*)(Hin + (size_t)cB0.x * 128 + q * 8);
        uint4 vB1 = *(const uint4*)(Hin + (size_t)cB1.x * 128 + q * 8);
        uint4 vB2 = *(const uint4*)(Hin + (size_t)cB2.x * 128 + q * 8);
        uint4 vB3 = *(const uint4*)(Hin + (size_t)cB3.x * 128 + q * 8);
        fma8(accA, __int_as_float(cA0.y), vA0);
        fma8(accA, __int_as_float(cA1.y), vA1);
        fma8(accA, __int_as_float(cA2.y), vA2);
        fma8(accA, __int_as_float(cA3.y), vA3);
        fma8(accB, __int_as_float(cB0.y), vB0);
        fma8(accB, __int_as_float(cB1.y), vB1);
        fma8(accB, __int_as_float(cB2.y), vB2);
        fma8(accB, __int_as_float(cB3.y), vB3);
        kA += 4; kB += 4;
    }

    {
        uint4 oA = make_uint4(pk2(accA[0], accA[1]), pk2(accA[2], accA[3]),
                              pk2(accA[4], accA[5]), pk2(accA[6], accA[7]));
        uint4 oB = make_uint4(pk2(accB[0], accB[1]), pk2(accB[2], accB[3]),
                              pk2(accB[4], accB[5]), pk2(accB[6], accB[7]));
        *(uint4*)&T[gi][q * 8] = oA;
        *(uint4*)&T[gi + 16][q * 8] = oB;
    }
    __syncthreads();

    // phase 2: MFMA from T
    const int wv = t >> 6;       // wave -> col slice [wv*32, wv*32+32)
    const int lane = t & 63;
    const int r15 = lane & 15;
    const int kg = lane >> 4;

    bf16x8 bfr[2][4];
#pragma unroll
    for (int nc = 0; nc < 2; nc++)
#pragma unroll
        for (int ks = 0; ks < 4; ks++)
            bfr[nc][ks] = *(const bf16x8*)&T[nc * 16 + r15][kg * 8 + ks * 32];

    f32x4 acc[2][2];
#pragma unroll
    for (int nc = 0; nc < 2; nc++)
#pragma unroll
        for (int c = 0; c < 2; c++) acc[nc][c] = (f32x4){0.f, 0.f, 0.f, 0.f};

#pragma unroll
    for (int c = 0; c < 2; c++) {
        const unsigned short* wrow = Wt + (size_t)(wv * 32 + c * 16 + r15) * 128 + kg * 8;
#pragma unroll
        for (int ks = 0; ks < 4; ks++) {
            bf16x8 afr = *(const bf16x8*)(wrow + ks * 32);
            acc[0][c] = __builtin_amdgcn_mfma_f32_16x16x32_bf16(afr, bfr[0][ks], acc[0][c], 0, 0, 0);
            acc[1][c] = __builtin_amdgcn_mfma_f32_16x16x32_bf16(afr, bfr[1][ks], acc[1][c], 0, 0, 0);
        }
    }
    __syncthreads();   // all waves done reading T; safe to overwrite

    // bias+relu, stage results into T[node_local][col]
#pragma unroll
    for (int nc = 0; nc < 2; nc++) {
#pragma unroll
        for (int c = 0; c < 2; c++) {
            int col = wv * 32 + c * 16 + kg * 4;
            float4 bv = *(const float4*)(bias + col);
            float v0 = fmaxf(acc[nc][c][0] + bv.x, 0.f);
            float v1 = fmaxf(acc[nc][c][1] + bv.y, 0.f);
            float v2 = fmaxf(acc[nc][c][2] + bv.z, 0.f);
            float v3 = fmaxf(acc[nc][c][3] + bv.w, 0.f);
            *(uint2*)&T[nc * 16 + r15][col] = make_uint2(pk2(v0, v1), pk2(v2, v3));
        }
    }
    __syncthreads();

    // cooperative full-line stores: 16 lanes x 16B = one 256B row per group
#pragma unroll
    for (int p = 0; p < 2; p++) {
        int row = p * 16 + gi;
        int node = nodeid[row];
        if (node >= 0) {
            *(uint4*)(Hout + (size_t)node * 128 + q * 8) = *(const uint4*)&T[row][q * 8];
        }
    }
}

// ---------------- last hidden layer + pooling (csT staged in LDS) ----------------
__global__ __launch_bounds__(256) void fused_hidden_last(
    const unsigned short* __restrict__ Hin,
    const int2* __restrict__ cw,
    const int4* __restrict__ srt,
    const unsigned short* __restrict__ Wt,
    const float* __restrict__ bias,
    const float* __restrict__ csT,      // [N][8] node-major colsum
    float* __restrict__ gsum,           // [NSLOT][8][128]
    int N)
{
    __shared__ __align__(16) unsigned short T[32][136];
    __shared__ int nodeid[32];
    __shared__ float cs[32][8];
    __shared__ float P[2][8][128];
    const int t = threadIdx.x;
    const int q = t & 15;
    const int gi = t >> 4;
    const int sbid = xcd_swizzle(blockIdx.x, gridDim.x);
    const int sA = sbid * 32 + gi;
    const int sB = sA + 16;
    int4 dA = (sA < N) ? srt[sA] : make_int4(-1, 0, 0, 0);
    int4 dB = (sB < N) ? srt[sB] : make_int4(-1, 0, 0, 0);
    if (q == 0) {
        nodeid[gi]      = dA.x;
        nodeid[gi + 16] = dB.x;
    }
    // stage csT rows for this block's nodes (q=0/1 lanes: 2 uint4 per node)
    if (q < 2) {
        const float* srcp0 = (dA.x >= 0) ? &csT[(size_t)dA.x * 8 + q * 4] : nullptr;
        const float* srcp1 = (dB.x >= 0) ? &csT[(size_t)dB.x * 8 + q * 4] : nullptr;
        float4 z = make_float4(0.f, 0.f, 0.f, 0.f);
        *(float4*)&cs[gi][q * 4]      = srcp0 ? *(const float4*)srcp0 : z;
        *(float4*)&cs[gi + 16][q * 4] = srcp1 ? *(const float4*)srcp1 : z;
    }

    float accA[8] = {0,0,0,0,0,0,0,0}, accB[8] = {0,0,0,0,0,0,0,0};
    int kA = 0, eA = 0, kB = 0, eB = 0;
    if (dA.x >= 0) {
        float dv = __int_as_float(dA.w);
        seed8(accA, dv * dv, *(const uint4*)(Hin + (size_t)dA.x * 128 + q * 8));
        kA = dA.y; eA = dA.z;
    }
    if (dB.x >= 0) {
        float dv = __int_as_float(dB.w);
        seed8(accB, dv * dv, *(const uint4*)(Hin + (size_t)dB.x * 128 + q * 8));
        kB = dB.y; eB = dB.z;
    }

    while (kA < eA || kB < eB) {
        int2 cA0 = (kA     < eA) ? cw[kA]     : make_int2(0, 0);
        int2 cA1 = (kA + 1 < eA) ? cw[kA + 1] : make_int2(0, 0);
        int2 cA2 = (kA + 2 < eA) ? cw[kA + 2] : make_int2(0, 0);
        int2 cA3 = (kA + 3 < eA) ? cw[kA + 3] : make_int2(0, 0);
        int2 cB0 = (kB     < eB) ? cw[kB]     : make_int2(0, 0);
        int2 cB1 = (kB + 1 < eB) ? cw[kB + 1] : make_int2(0, 0);
        int2 cB2 = (kB + 2 < eB) ? cw[kB + 2] : make_int2(0, 0);
        int2 cB3 = (kB + 3 < eB) ? cw[kB + 3] : make_int2(0, 0);
        uint4 vA0 = *(const uint4*)(Hin + (size_t)cA0.x * 128 + q * 8);
        uint4 vA1 = *(const uint4*)(Hin + (size_t)cA1.x * 128 + q * 8);
        uint4 vA2 = *(const uint4*)(Hin + (size_t)cA2.x * 128 + q * 8);
        uint4 vA3 = *(const uint4*)(Hin + (size_t)cA3.x * 128 + q * 8);
        uint4 vB0 = *(const uint4*)(Hin + (size_t)cB0.x * 128 + q * 8);
        uint4 vB1 = *(const uint4*)(Hin + (size_t)cB1.x * 128 + q * 8);
        uint4 vB2 = *(const uint4*)(Hin + (size_t)cB2.x * 128 + q * 8);
        uint4 vB3 = *(const uint4*)(Hin + (size_t)cB3.x * 128 + q * 8);
        fma8(accA, __int_as_float(cA0.y), vA0);
        fma8(accA, __int_as_float(cA1.y), vA1);
        fma8(accA, __int_as_float(cA2.y), vA2);
        fma8(accA, __int_as_float(cA3.y), vA3);
        fma8(accB, __int_as_float(cB0.y), vB0);
        fma8(accB, __int_as_float(cB1.y), vB1);
        fma8(accB, __int_as_float(cB2.y), vB2);
        fma8(accB, __int_as_float(cB3.y), vB3);
        kA += 4; kB += 4;
    }

    {
        uint4 oA = make_uint4(pk2(accA[0], accA[1]), pk2(accA[2], accA[3]),
                              pk2(accA[4], accA[5]), pk2(accA[6], accA[7]));
        uint4 oB = make_uint4(pk2(accB[0], accB[1]), pk2(accB[2], accB[3]),
                              pk2(accB[4], accB[5]), pk2(accB[6], accB[7]));
        *(uint4*)&T[gi][q * 8] = oA;
        *(uint4*)&T[gi + 16][q * 8] = oB;
    }
    __syncthreads();

    const int wv = t >> 6;
    const int lane = t & 63;
    const int r15 = lane & 15;
    const int kg = lane >> 4;

    bf16x8 bfr[2][4];
#pragma unroll
    for (int nc = 0; nc < 2; nc++)
#pragma unroll
        for (int ks = 0; ks < 4; ks++)
            bfr[nc][ks] = *(const bf16x8*)&T[nc * 16 + r15][kg * 8 + ks * 32];

    f32x4 acc[2][2];
#pragma unroll
    for (int nc = 0; nc < 2; nc++)
#pragma unroll
        for (int c = 0; c < 2; c++) acc[nc][c] = (f32x4){0.f, 0.f, 0.f, 0.f};

#pragma unroll
    for (int c = 0; c < 2; c++) {
        const unsigned short* wrow = Wt + (size_t)(wv * 32 + c * 16 + r15) * 128 + kg * 8;
#pragma unroll
        for (int ks = 0; ks < 4; ks++) {
            bf16x8 afr = *(const bf16x8*)(wrow + ks * 32);
            acc[0][c] = __builtin_amdgcn_mfma_f32_16x16x32_bf16(afr, bfr[0][ks], acc[0][c], 0, 0, 0);
            acc[1][c] = __builtin_amdgcn_mfma_f32_16x16x32_bf16(afr, bfr[1][ks], acc[1][c], 0, 0, 0);
        }
    }
    __syncthreads();

    // bias+relu, stage h4 rows into T
#pragma unroll
    for (int nc = 0; nc < 2; nc++) {
#pragma unroll
        for (int c = 0; c < 2; c++) {
            int col = wv * 32 + c * 16 + kg * 4;
            float4 bv = *(const float4*)(bias + col);
            float v0 = fmaxf(acc[nc][c][0] + bv.x, 0.f);
            float v1 = fmaxf(acc[nc][c][1] + bv.y, 0.f);
            float v2 = fmaxf(acc[nc][c][2] + bv.z, 0.f);
            float v3 = fmaxf(acc[nc][c][3] + bv.w, 0.f);
            *(uint2*)&T[nc * 16 + r15][col] = make_uint2(pk2(v0, v1), pk2(v2, v3));
        }
    }
    __syncthreads();

    // pooling epilogue: thread (f, half) accumulates 16 rows x 8 graphs from LDS cs
    {
        const int f = t & 127;
        const int half = t >> 7;
        float pacc[8] = {0,0,0,0,0,0,0,0};
        for (int r = 0; r < 16; r++) {
            int row = half * 16 + r;
            float val = bflo((unsigned int)T[row][f]);
#pragma unroll
            for (int g = 0; g < 8; g++)
                pacc[g] = fmaf(cs[row][g], val, pacc[g]);
        }
#pragma unroll
        for (int g = 0; g < 8; g++) P[half][g][f] = pacc[g];
        __syncthreads();
        if (half == 0) {
            int slot = sbid & (NSLOT - 1);
#pragma unroll
            for (int g = 0; g < 8; g++)
                atomicAdd(&gsum[((size_t)slot * 8 + g) * 128 + f], P[0][g][f] + P[1][g][f]);
        }
    }
}

// ---------------- colsum transposed: csT[j][g] = sum_{i in g} A_hat_ij ----------------
__global__ void colsumT_k(const int* __restrict__ src, const int* __restrict__ dst,
                          const int* __restrict__ batch, const float* __restrict__ dinv,
                          float* __restrict__ csT, int N, int E) {
    int e = blockIdx.x * 256 + threadIdx.x;
    if (e < E) {
        int s = src[e], d = dst[e];
        atomicAdd(&csT[(size_t)s * 8 + batch[d]], dinv[s] * dinv[d]);
    } else if (e < E + N) {
        int i = e - E;
        float di = dinv[i];
        atomicAdd(&csT[(size_t)i * 8 + batch[i]], di * di);
    }
}

// ---------------- final: sg = sum slots; out = sigmoid(sg @ W_out / c + b) ----------------
__global__ void final6_k(const float* __restrict__ gsum, const int* __restrict__ gstart,
                         const float* __restrict__ W_out, const float* __restrict__ b_out,
                         float* __restrict__ out) {
    __shared__ float sg[8][128];
    int t = threadIdx.x;  // 512
    for (int i = t; i < 1024; i += 512) {
        int g = i >> 7, k = i & 127;
        float s = 0.f;
        for (int sl = 0; sl < NSLOT; sl++) s += gsum[((size_t)sl * 8 + g) * 128 + k];
        sg[g][k] = s;
    }
    __syncthreads();
    int g = t / 64, f = t % 64;
    float dot = 0.f;
    for (int k = 0; k < 128; k++) dot = fmaf(sg[g][k], W_out[k * 64 + f], dot);
    int c = gstart[g + 1] - gstart[g];
    float v = dot / (float)max(c, 1) + b_out[f];
    out[g * 64 + f] = 1.f / (1.f + expf(-v));
}

// ---------------- launch ----------------
extern "C" void kernel_launch(void* const* d_in, const int* in_sizes, int n_in,
                              void* d_out, int out_size, void* d_ws, size_t ws_size,
                              hipStream_t stream) {
    const float* x     = (const float*)d_in[0];
    const int*   ei    = (const int*)d_in[1];
    const int*   batch = (const int*)d_in[2];
    const float* W_in  = (const float*)d_in[3];
    const float* b_in  = (const float*)d_in[4];
    const float* W_h   = (const float*)d_in[5];
    const float* b_h   = (const float*)d_in[6];
    const float* W_out = (const float*)d_in[7];
    const float* b_out = (const float*)d_in[8];

    const int N = in_sizes[2];
    const int E = in_sizes[1] / 2;
    const int L = in_sizes[5] / (INTER * INTER);
    const int G = 8;
    const int* src = ei;
    const int* dst = ei + E;
    const int nblk = (N + 255) / 256;
    const int nbh = NBIN * nblk;              // blockhist size

    char* ws = (char*)d_ws;
    size_t off = 0;
    auto alloc = [&](size_t bytes) -> void* {
        void* p = ws + off;
        off += (bytes + 255) & ~(size_t)255;
        return p;
    };
    int*   cnt    = (int*)alloc((size_t)N * 4);
    int*   cursor = (int*)alloc((size_t)N * 4);   // adjacent to cnt: one memset covers both
    int*   rs     = (int*)alloc((size_t)(N + 1) * 4);
    int*   bsums  = (int*)alloc(4096);
    float* dinv   = (float*)alloc((size_t)N * 4);
    int2*  cw     = (int2*)alloc((size_t)E * 8);
    unsigned short* h   = (unsigned short*)alloc((size_t)N * INTER * 2);
    unsigned short* h2  = (unsigned short*)alloc((size_t)N * INTER * 2);
    unsigned short* Wht = (unsigned short*)alloc((size_t)L * INTER * INTER * 2);
    float* csT    = (float*)alloc((size_t)N * 8 * 4);
    float* gsum   = (float*)alloc((size_t)NSLOT * 8 * 128 * 4);
    int*   gstart = (int*)alloc((G + 1) * 4);
    int*   bh     = (int*)alloc((size_t)(nbh + 1) * 4);
    int4*  srt    = (int4*)alloc((size_t)N * 16);
    (void)ws_size; (void)n_in;

    hipMemsetAsync(cnt, 0, (size_t)N * 8, stream);   // cnt + cursor (adjacent)
    hipMemsetAsync(csT, 0, (size_t)N * 8 * 4, stream);
    hipMemsetAsync(gsum, 0, (size_t)NSLOT * 8 * 128 * 4, stream);

    // CSR build
    count_k<<<(E + 255) / 256, 256, 0, stream>>>(dst, cnt, E);
    int nsb = (N + SCAN_E - 1) / SCAN_E;
    scan_block<<<nsb, SCAN_T, 0, stream>>>(cnt, rs, bsums, N);
    scan_block<<<1, SCAN_T, 0, stream>>>(bsums, bsums, nullptr, nsb);
    scan_add<<<nsb, SCAN_T, 0, stream>>>(rs, bsums, N, E);
    prep2_k<<<nblk, 256, 0, stream>>>(cnt, batch, dinv, bh, gstart, N, G, nblk);
    scatter_k<<<(E + 255) / 256, 256, 0, stream>>>(src, dst, rs, cursor, dinv, cw, E);
    colsumT_k<<<(E + N + 255) / 256, 256, 0, stream>>>(src, dst, batch, dinv, csT, N, E);

    // counting-sort scan + scatter -> srt
    int nsb2 = (nbh + SCAN_E - 1) / SCAN_E;
    scan_block<<<nsb2, SCAN_T, 0, stream>>>(bh, bh, bsums, nbh);
    scan_block<<<1, SCAN_T, 0, stream>>>(bsums, bsums, nullptr, nsb2);
    scan_add<<<nsb2, SCAN_T, 0, stream>>>(bh, bsums, nbh, N);
    dorder3_k<<<nblk, 256, 0, stream>>>(cnt, batch, rs, dinv, bh, srt, N, nblk);

    // weight prep
    wprep_h<<<(L * INTER * INTER + 255) / 256, 256, 0, stream>>>(W_h, Wht, L);

    // input layer (fused aggregate + transform)
    agg_in_k<<<nblk, 256, 0, stream>>>(x, rs, cw, dinv, W_in, b_in, h, N);

    // hidden layers: first L-1 standard, last fused with pooling
    unsigned short* hin = h;
    unsigned short* hout = h2;
    for (int l = 0; l < L - 1; l++) {
        fused_hidden8<<<(N + 31) / 32, 256, 0, stream>>>(
            hin, cw, srt, Wht + (size_t)l * INTER * INTER, b_h + (size_t)l * INTER, hout, N);
        unsigned short* tmp = hin; hin = hout; hout = tmp;
    }
    fused_hidden_last<<<(N + 31) / 32, 256, 0, stream>>>(
        hin, cw, srt, Wht + (size_t)(L - 1) * INTER * INTER, b_h + (size_t)(L - 1) * INTER,
        csT, gsum, N);

    // final: slot-sum, matmul with W_out (fp32), mean, bias, sigmoid
    final6_k<<<1, 512, 0, stream>>>(gsum, gstart, W_out, b_out, (float*)d_out);
}